// Round 2
// baseline (4613.208 us; speedup 1.0000x reference)
//
#include <hip/hip_runtime.h>
#include <math.h>

#define B_   16
#define N_   2048
#define S_   1025
#define K_   16
#define EMB_ 64
#define NF_  (B_ * S_ * K_)   // 262400
#define NCH_ (NF_ / 64)       // 4100 column-chunks of 64

// ---------------- FPS: one block (256 thr) per batch, fp64-exact distances ----------------
__global__ __launch_bounds__(256) void fps_kernel(const float* __restrict__ xy,
                                                  int* __restrict__ fps_idx,
                                                  float* __restrict__ new_xyz,
                                                  float* __restrict__ out0) {
  const int b = blockIdx.x;
  const int tid = threadIdx.x;
  __shared__ float lx[N_], ly[N_];
  __shared__ double bv[4];
  __shared__ int bi[4];
  const float* xb = xy + (size_t)b * 2 * N_;
  float px[8], py[8];
  double dist[8];
#pragma unroll
  for (int j = 0; j < 8; ++j) {
    int p = tid + 256 * j;
    float x = xb[p];
    float y = xb[N_ + p];
    lx[p] = x; ly[p] = y;
    px[j] = x; py[j] = y;
    dist[j] = __builtin_inf();
  }
  __syncthreads();
  int cur = 0;
  const int lane = tid & 63, wv = tid >> 6;
  for (int t = 0; t < S_; ++t) {
    if (tid == 0) {
      fps_idx[b * S_ + t] = cur;
      float nx = lx[cur], ny = ly[cur];
      new_xyz[(b * S_ + t) * 2 + 0] = nx;
      new_xyz[(b * S_ + t) * 2 + 1] = ny;
      out0[b * 2 * S_ + t] = nx;
      out0[b * 2 * S_ + S_ + t] = ny;
    }
    const double cx = (double)lx[cur], cy = (double)ly[cur];
    double best = -__builtin_inf();
    int bidx = 0;
#pragma unroll
    for (int j = 0; j < 8; ++j) {
      double dx = (double)px[j] - cx;
      double dy = (double)py[j] - cy;
      double d = dx * dx + dy * dy;     // exact in fp64 for fp32 inputs
      d = (d < dist[j]) ? d : dist[j];
      dist[j] = d;
      if (d > best) { best = d; bidx = tid + 256 * j; }  // ascending idx -> strict > keeps lowest
    }
#pragma unroll
    for (int m = 1; m < 64; m <<= 1) {
      double v2 = __shfl_xor(best, m, 64);
      int i2 = __shfl_xor(bidx, m, 64);
      if (v2 > best || (v2 == best && i2 < bidx)) { best = v2; bidx = i2; }
    }
    __syncthreads();
    if (lane == 0) { bv[wv] = best; bi[wv] = bidx; }
    __syncthreads();
    double v = bv[0]; int vi = bi[0];
#pragma unroll
    for (int w = 1; w < 4; ++w) {
      double v2 = bv[w]; int i2 = bi[w];
      if (v2 > v || (v2 == v && i2 < vi)) { v = v2; vi = i2; }
    }
    cur = vi;
  }
}

// ---------------- KNN in fp64 (only for FPS-selected points) ----------------
__global__ __launch_bounds__(256) void knn_kernel(const float* __restrict__ xy,
                                                  const int* __restrict__ fps_idx,
                                                  int* __restrict__ knn_sel) {
  const int b = blockIdx.y;
  __shared__ double lxd[N_], lyd[N_], lsq[N_];   // 48 KB
  const float* xb = xy + (size_t)b * 2 * N_;
  for (int p = threadIdx.x; p < N_; p += 256) {
    double x = (double)xb[p], y = (double)xb[N_ + p];
    lxd[p] = x; lyd[p] = y;
    lsq[p] = x * x + y * y;            // exact
  }
  __syncthreads();
  const int s = blockIdx.x * 256 + threadIdx.x;
  if (s >= S_) return;
  const int p0 = fps_idx[b * S_ + s];
  const double xn = lxd[p0], yn = lyd[p0], sqn = lsq[p0];
  double d16[K_];
  int i16[K_];
#pragma unroll
  for (int j = 0; j < K_; ++j) { d16[j] = __builtin_inf(); i16[j] = 0; }
  for (int m = 0; m < N_; ++m) {
    double dot = xn * lxd[m] + yn * lyd[m];          // exact
    double dd = (sqn - 2.0 * dot) + lsq[m];          // matches ref expression order
    if (dd < d16[K_ - 1]) {   // strict < : ties keep lower index (stable top_k)
#pragma unroll
      for (int j = K_ - 1; j >= 1; --j) {
        bool shift = dd < d16[j - 1];
        bool ins = dd < d16[j];
        d16[j] = shift ? d16[j - 1] : (ins ? dd : d16[j]);
        i16[j] = shift ? i16[j - 1] : (ins ? m : i16[j]);
      }
      if (dd < d16[0]) { d16[0] = dd; i16[0] = m; }
    }
  }
  int* dst = knn_sel + ((size_t)b * S_ + s) * K_;
#pragma unroll
  for (int j = 0; j < K_; ++j) dst[j] = i16[j];
}

// ---------------- P[b][pt][c] = sum_e W1[c][2+e] * fea[b][e][pt] ----------------
__global__ __launch_bounds__(256) void pk_kernel(const float* __restrict__ fea,
                                                 const float* __restrict__ W1,
                                                 float* __restrict__ P) {
  const int t = threadIdx.x;
  const int b = blockIdx.x >> 5;
  const int pt0 = (blockIdx.x & 31) << 6;
  __shared__ float W1L[64 * 64];   // [e][c]
  __shared__ float feaL[64 * 64];  // [e][pt]
#pragma unroll
  for (int p = 0; p < 16; ++p) {
    int idx = t + 256 * p;
    int c = idx >> 6, e = idx & 63;
    W1L[e * 64 + c] = W1[c * 66 + 2 + e];
    int r = (t >> 6) + 4 * p, cc = t & 63;
    feaL[r * 64 + cc] = fea[((size_t)b * 64 + r) * N_ + pt0 + cc];
  }
  __syncthreads();
  const int tpt = t & 15, tcq = t >> 4;
  float acc[4][4];
#pragma unroll
  for (int i = 0; i < 4; ++i)
#pragma unroll
    for (int j = 0; j < 4; ++j) acc[i][j] = 0.f;
  for (int e = 0; e < 64; ++e) {
    float4 a4 = *reinterpret_cast<const float4*>(&W1L[e * 64 + tcq * 4]);
    float4 b4 = *reinterpret_cast<const float4*>(&feaL[e * 64 + tpt * 4]);
    const float av[4] = {a4.x, a4.y, a4.z, a4.w};
    const float bvv[4] = {b4.x, b4.y, b4.z, b4.w};
#pragma unroll
    for (int i = 0; i < 4; ++i)
#pragma unroll
      for (int j = 0; j < 4; ++j) acc[i][j] = fmaf(av[i], bvv[j], acc[i][j]);
  }
#pragma unroll
  for (int j = 0; j < 4; ++j) {
    int pt = tpt * 4 + j;
    float4 v = {acc[0][j], acc[1][j], acc[2][j], acc[3][j]};
    *reinterpret_cast<float4*>(&P[((size_t)(b * N_ + pt0 + pt)) * 64 + tcq * 4]) = v;
  }
}

// ---------------- Y1[64][NF]: gather P + W1a*dxy + b1 ----------------
__global__ __launch_bounds__(256) void yk1_kernel(const float* __restrict__ xy,
                                                  const int* __restrict__ knn_sel,
                                                  const float* __restrict__ new_xyz,
                                                  const float* __restrict__ P,
                                                  const float* __restrict__ W1,
                                                  const float* __restrict__ b1,
                                                  float* __restrict__ Y1) {
  __shared__ float w0s[64], w1s[64], bbs[64];
  const int t = threadIdx.x;
  if (t < 64) { w0s[t] = W1[t * 66 + 0]; w1s[t] = W1[t * 66 + 1]; bbs[t] = b1[t]; }
  __syncthreads();
  const int n = blockIdx.x * 256 + t;
  const int bs = n >> 4;
  const int b = bs / S_;
  const int nbr = knn_sel[n];
  const float dx = xy[(size_t)b * 2 * N_ + nbr] - new_xyz[bs * 2 + 0];
  const float dy = xy[(size_t)b * 2 * N_ + N_ + nbr] - new_xyz[bs * 2 + 1];
  const float* prow = &P[((size_t)(b * N_ + nbr)) * 64];
  for (int c4 = 0; c4 < 64; c4 += 4) {
    float4 p4 = *reinterpret_cast<const float4*>(&prow[c4]);
    float v0 = p4.x + w0s[c4 + 0] * dx + w1s[c4 + 0] * dy + bbs[c4 + 0];
    float v1 = p4.y + w0s[c4 + 1] * dx + w1s[c4 + 1] * dy + bbs[c4 + 1];
    float v2 = p4.z + w0s[c4 + 2] * dx + w1s[c4 + 2] * dy + bbs[c4 + 2];
    float v3 = p4.w + w0s[c4 + 3] * dx + w1s[c4 + 3] * dy + bbs[c4 + 3];
    Y1[(size_t)(c4 + 0) * NF_ + n] = v0;
    Y1[(size_t)(c4 + 1) * NF_ + n] = v1;
    Y1[(size_t)(c4 + 2) * NF_ + n] = v2;
    Y1[(size_t)(c4 + 3) * NF_ + n] = v3;
  }
}

// ---------------- per-row sum (optionally affine+relu), double accumulators ----------------
template <bool AFF>
__global__ __launch_bounds__(1024) void rowsum_kernel(const float* __restrict__ Y,
                                                      const float* __restrict__ A,
                                                      const float* __restrict__ Bc,
                                                      double* __restrict__ out) {
  const int r = blockIdx.x;
  const float a = AFF ? A[r] : 0.f, c = AFF ? Bc[r] : 0.f;
  double s = 0.0;
  for (int i = threadIdx.x; i < NF_; i += 1024) {
    float v = Y[(size_t)r * NF_ + i];
    if (AFF) v = fmaxf(fmaf(v, a, c), 0.f);
    s += (double)v;
  }
  __shared__ double sh[1024];
  sh[threadIdx.x] = s;
  __syncthreads();
  for (int o = 512; o > 0; o >>= 1) {
    if (threadIdx.x < o) sh[threadIdx.x] += sh[threadIdx.x + o];
    __syncthreads();
  }
  if (threadIdx.x == 0) out[r] = sh[0];
}

// ---------------- per-row centered sumsq ----------------
__global__ __launch_bounds__(1024) void rowvar_kernel(const float* __restrict__ Y,
                                                      const double* __restrict__ sums,
                                                      double* __restrict__ out) {
  const int r = blockIdx.x;
  const double mu = sums[r] * (1.0 / NF_);
  double s = 0.0;
  for (int i = threadIdx.x; i < NF_; i += 1024) {
    double d = (double)Y[(size_t)r * NF_ + i] - mu;
    s += d * d;
  }
  __shared__ double sh[1024];
  sh[threadIdx.x] = s;
  __syncthreads();
  for (int o = 512; o > 0; o >>= 1) {
    if (threadIdx.x < o) sh[threadIdx.x] += sh[threadIdx.x + o];
    __syncthreads();
  }
  if (threadIdx.x == 0) out[r] = sh[0];
}

// ---------------- A = g*rsqrt(var+eps); D = be - A*mu ----------------
__global__ void absch_kernel(const double* __restrict__ muv, const double* __restrict__ varraw,
                             const float* __restrict__ g, const float* __restrict__ be,
                             float* __restrict__ A, float* __restrict__ D, int M, int mu_is_sum) {
  int m = threadIdx.x;
  if (m >= M) return;
  double mu = mu_is_sum ? muv[m] * (1.0 / NF_) : muv[m];
  double var = varraw[m] * (1.0 / NF_);
  double a = (double)g[m] / sqrt(var + 1e-5);
  A[m] = (float)a;
  D[m] = (float)((double)be[m] - a * mu);
}

// ---------------- mu[m] = dot(W[m,:K], S)/NF ----------------
__global__ void meanlin_kernel(const float* __restrict__ W, const double* __restrict__ S,
                               double* __restrict__ mu, int M, int K) {
  int m = threadIdx.x;
  if (m >= M) return;
  double acc = 0.0;
  for (int k = 0; k < K; ++k) acc += (double)W[m * K + k] * S[k];
  mu[m] = acc * (1.0 / NF_);
}

// ---------------- reduce partials [P][M] -> double[M] ----------------
__global__ void red_kernel(const float* __restrict__ parts, double* __restrict__ out, int P, int M) {
  int m = threadIdx.x;
  if (m >= M) return;
  double a = 0.0;
  for (int p = 0; p < P; ++p) a += (double)parts[(size_t)p * M + m];
  out[m] = a;
}

// ============ GEMM2 pass kernels: y2[128][64cols] per chunk, x1 from Y1 on the fly ============
// thread map phase A: tmA = t>>4 (8 rows each, m=tmA*8+i), tcA = t&15 (4 cols each)

// MODE 0: accumulate (y2-mu2')^2 ;  MODE 1: accumulate relu(A2*y2+D2)
template <int MODE>
__global__ __launch_bounds__(256) void pass2_kernel(const float* __restrict__ Y1,
                                                    const float* __restrict__ W2,
                                                    const float* __restrict__ A1v,
                                                    const float* __restrict__ Bc1v,
                                                    const double* __restrict__ mu2p,
                                                    const float* __restrict__ A2v,
                                                    const float* __restrict__ D2v,
                                                    float* __restrict__ parts) {
  __shared__ float W2L[64 * 128];
  __shared__ float ab[128];
  __shared__ float vpart[16][128];
  const int t = threadIdx.x;
#pragma unroll
  for (int p = 0; p < 32; ++p) {
    int idx = t + 256 * p;
    int m = idx >> 6, k = idx & 63;
    W2L[k * 128 + m] = W2[m * 64 + k];
  }
  if (t < 64) { ab[t] = A1v[t]; ab[64 + t] = Bc1v[t]; }
  const int tmA = t >> 4, tcA = t & 15;
  float par0[8], par1[8], vacc[8];
#pragma unroll
  for (int i = 0; i < 8; ++i) {
    int m = tmA * 8 + i;
    if (MODE == 0) { par0[i] = (float)mu2p[m]; par1[i] = 0.f; }
    else { par0[i] = A2v[m]; par1[i] = D2v[m]; }
    vacc[i] = 0.f;
  }
  __syncthreads();
  for (int ch = blockIdx.x; ch < NCH_; ch += 512) {
    const size_t n0 = (size_t)ch * 64;
    float acc[8][4];
#pragma unroll
    for (int i = 0; i < 8; ++i)
#pragma unroll
      for (int j = 0; j < 4; ++j) acc[i][j] = 0.f;
#pragma unroll 2
    for (int k = 0; k < 64; ++k) {
      float4 y4 = *reinterpret_cast<const float4*>(&Y1[(size_t)k * NF_ + n0 + tcA * 4]);
      float a1 = ab[k], c1 = ab[64 + k];
      float bx[4];
      bx[0] = fmaxf(fmaf(y4.x, a1, c1), 0.f);
      bx[1] = fmaxf(fmaf(y4.y, a1, c1), 0.f);
      bx[2] = fmaxf(fmaf(y4.z, a1, c1), 0.f);
      bx[3] = fmaxf(fmaf(y4.w, a1, c1), 0.f);
      const float4* ap = reinterpret_cast<const float4*>(&W2L[k * 128 + tmA * 8]);
      float4 a0 = ap[0], a4 = ap[1];
      const float av[8] = {a0.x, a0.y, a0.z, a0.w, a4.x, a4.y, a4.z, a4.w};
#pragma unroll
      for (int i = 0; i < 8; ++i)
#pragma unroll
        for (int j = 0; j < 4; ++j) acc[i][j] = fmaf(av[i], bx[j], acc[i][j]);
    }
#pragma unroll
    for (int i = 0; i < 8; ++i)
#pragma unroll
      for (int j = 0; j < 4; ++j) {
        if (MODE == 0) {
          float d = acc[i][j] - par0[i];
          vacc[i] = fmaf(d, d, vacc[i]);
        } else {
          vacc[i] += fmaxf(fmaf(acc[i][j], par0[i], par1[i]), 0.f);
        }
      }
  }
#pragma unroll
  for (int i = 0; i < 8; ++i) vpart[tcA][tmA * 8 + i] = vacc[i];
  __syncthreads();
  if (t < 128) {
    float s = 0.f;
    for (int q = 0; q < 16; ++q) s += vpart[q][t];
    parts[(size_t)blockIdx.x * 128 + t] = s;
  }
}

// ============ var3 pass: y3 = W3 * relu(A2*(W2*x1)+D2), accumulate (y3-mu3')^2 ============
__global__ __launch_bounds__(256) void var3_kernel(const float* __restrict__ Y1,
                                                   const float* __restrict__ W2,
                                                   const float* __restrict__ W3,
                                                   const float* __restrict__ A1v,
                                                   const float* __restrict__ Bc1v,
                                                   const float* __restrict__ A2v,
                                                   const float* __restrict__ D2v,
                                                   const double* __restrict__ mu3p,
                                                   float* __restrict__ parts) {
  __shared__ float W2L[64 * 128];     // persistent
  __shared__ float ab[128];
  __shared__ float X2s[128 * 68];
  __shared__ float W3c[16 * 256];
  __shared__ float vpart3[8][256];
  const int t = threadIdx.x;
#pragma unroll
  for (int p = 0; p < 32; ++p) {
    int idx = t + 256 * p;
    int m = idx >> 6, k = idx & 63;
    W2L[k * 128 + m] = W2[m * 64 + k];
  }
  if (t < 64) { ab[t] = A1v[t]; ab[64 + t] = Bc1v[t]; }
  const int tmA = t >> 4, tcA = t & 15;
  const int tm3 = t & 31, tcol = t >> 5;
  float a2r[8], d2r[8], mu3[8], vacc[8];
#pragma unroll
  for (int i = 0; i < 8; ++i) {
    a2r[i] = A2v[tmA * 8 + i];
    d2r[i] = D2v[tmA * 8 + i];
    mu3[i] = (float)mu3p[tm3 * 8 + i];
    vacc[i] = 0.f;
  }
  __syncthreads();
  for (int ch = blockIdx.x; ch < NCH_; ch += 256) {
    const size_t n0 = (size_t)ch * 64;
    // phase A
    {
      float acc[8][4];
#pragma unroll
      for (int i = 0; i < 8; ++i)
#pragma unroll
        for (int j = 0; j < 4; ++j) acc[i][j] = 0.f;
#pragma unroll 2
      for (int k = 0; k < 64; ++k) {
        float4 y4 = *reinterpret_cast<const float4*>(&Y1[(size_t)k * NF_ + n0 + tcA * 4]);
        float a1 = ab[k], c1 = ab[64 + k];
        float bx[4];
        bx[0] = fmaxf(fmaf(y4.x, a1, c1), 0.f);
        bx[1] = fmaxf(fmaf(y4.y, a1, c1), 0.f);
        bx[2] = fmaxf(fmaf(y4.z, a1, c1), 0.f);
        bx[3] = fmaxf(fmaf(y4.w, a1, c1), 0.f);
        const float4* ap = reinterpret_cast<const float4*>(&W2L[k * 128 + tmA * 8]);
        float4 a0 = ap[0], a4 = ap[1];
        const float av[8] = {a0.x, a0.y, a0.z, a0.w, a4.x, a4.y, a4.z, a4.w};
#pragma unroll
        for (int i = 0; i < 8; ++i)
#pragma unroll
          for (int j = 0; j < 4; ++j) acc[i][j] = fmaf(av[i], bx[j], acc[i][j]);
      }
#pragma unroll
      for (int i = 0; i < 8; ++i) {
        float4 v;
        v.x = fmaxf(fmaf(acc[i][0], a2r[i], d2r[i]), 0.f);
        v.y = fmaxf(fmaf(acc[i][1], a2r[i], d2r[i]), 0.f);
        v.z = fmaxf(fmaf(acc[i][2], a2r[i], d2r[i]), 0.f);
        v.w = fmaxf(fmaf(acc[i][3], a2r[i], d2r[i]), 0.f);
        *reinterpret_cast<float4*>(&X2s[(tmA * 8 + i) * 68 + tcA * 4]) = v;
      }
    }
    __syncthreads();
    // phase B: GEMM3
    float acc3[8][8];
#pragma unroll
    for (int i = 0; i < 8; ++i)
#pragma unroll
      for (int j = 0; j < 8; ++j) acc3[i][j] = 0.f;
    for (int kc = 0; kc < 8; ++kc) {
#pragma unroll
      for (int q = 0; q < 4; ++q) {
        float4 w = *reinterpret_cast<const float4*>(&W3[(size_t)t * 128 + kc * 16 + q * 4]);
        W3c[(q * 4 + 0) * 256 + t] = w.x;
        W3c[(q * 4 + 1) * 256 + t] = w.y;
        W3c[(q * 4 + 2) * 256 + t] = w.z;
        W3c[(q * 4 + 3) * 256 + t] = w.w;
      }
      __syncthreads();
#pragma unroll
      for (int kk = 0; kk < 16; ++kk) {
        const float4* ap = reinterpret_cast<const float4*>(&W3c[kk * 256 + tm3 * 8]);
        float4 a0 = ap[0], a4 = ap[1];
        const float4* bp = reinterpret_cast<const float4*>(&X2s[(kc * 16 + kk) * 68 + tcol * 8]);
        float4 b0 = bp[0], b4 = bp[1];
        const float av[8] = {a0.x, a0.y, a0.z, a0.w, a4.x, a4.y, a4.z, a4.w};
        const float bw[8] = {b0.x, b0.y, b0.z, b0.w, b4.x, b4.y, b4.z, b4.w};
#pragma unroll
        for (int i = 0; i < 8; ++i)
#pragma unroll
          for (int j = 0; j < 8; ++j) acc3[i][j] = fmaf(av[i], bw[j], acc3[i][j]);
      }
      __syncthreads();
    }
#pragma unroll
    for (int i = 0; i < 8; ++i)
#pragma unroll
      for (int j = 0; j < 8; ++j) {
        float d = acc3[i][j] - mu3[i];
        vacc[i] = fmaf(d, d, vacc[i]);
      }
    __syncthreads();  // X2s safe to overwrite next chunk
  }
#pragma unroll
  for (int i = 0; i < 8; ++i) vpart3[tcol][tm3 * 8 + i] = vacc[i];
  __syncthreads();
  {
    float s = 0.f;
    for (int q = 0; q < 8; ++q) s += vpart3[q][t];
    parts[(size_t)blockIdx.x * 256 + t] = s;
  }
}

// ============ final pass: GEMM2 -> BN -> relu -> GEMM3 -> BN -> max over k -> relu -> out1 ============
__global__ __launch_bounds__(256) void final_kernel(const float* __restrict__ Y1,
                                                    const float* __restrict__ W2,
                                                    const float* __restrict__ W3,
                                                    const float* __restrict__ A1v,
                                                    const float* __restrict__ Bc1v,
                                                    const float* __restrict__ A2v,
                                                    const float* __restrict__ D2v,
                                                    const float* __restrict__ A3v,
                                                    const float* __restrict__ D3v,
                                                    float* __restrict__ out1) {
  __shared__ float W2L[64 * 128];   // aliased as W3c in phase B
  __shared__ float ab[128];
  __shared__ float X2s[128 * 68];
  float* W3c = W2L;
  const int t = threadIdx.x;
#pragma unroll
  for (int p = 0; p < 32; ++p) {
    int idx = t + 256 * p;
    int m = idx >> 6, k = idx & 63;
    W2L[k * 128 + m] = W2[m * 64 + k];
  }
  if (t < 64) { ab[t] = A1v[t]; ab[64 + t] = Bc1v[t]; }
  const int tmA = t >> 4, tcA = t & 15;
  const int tm3 = t & 31, tcol = t >> 5;
  float a2r[8], d2r[8], a3r[8], d3r[8];
#pragma unroll
  for (int i = 0; i < 8; ++i) {
    a2r[i] = A2v[tmA * 8 + i];
    d2r[i] = D2v[tmA * 8 + i];
    a3r[i] = A3v[tm3 * 8 + i];
    d3r[i] = D3v[tm3 * 8 + i];
  }
  __syncthreads();
  const int ch = blockIdx.x;
  const size_t n0 = (size_t)ch * 64;
  // phase A
  {
    float acc[8][4];
#pragma unroll
    for (int i = 0; i < 8; ++i)
#pragma unroll
      for (int j = 0; j < 4; ++j) acc[i][j] = 0.f;
#pragma unroll 2
    for (int k = 0; k < 64; ++k) {
      float4 y4 = *reinterpret_cast<const float4*>(&Y1[(size_t)k * NF_ + n0 + tcA * 4]);
      float a1 = ab[k], c1 = ab[64 + k];
      float bx[4];
      bx[0] = fmaxf(fmaf(y4.x, a1, c1), 0.f);
      bx[1] = fmaxf(fmaf(y4.y, a1, c1), 0.f);
      bx[2] = fmaxf(fmaf(y4.z, a1, c1), 0.f);
      bx[3] = fmaxf(fmaf(y4.w, a1, c1), 0.f);
      const float4* ap = reinterpret_cast<const float4*>(&W2L[k * 128 + tmA * 8]);
      float4 a0 = ap[0], a4 = ap[1];
      const float av[8] = {a0.x, a0.y, a0.z, a0.w, a4.x, a4.y, a4.z, a4.w};
#pragma unroll
      for (int i = 0; i < 8; ++i)
#pragma unroll
        for (int j = 0; j < 4; ++j) acc[i][j] = fmaf(av[i], bx[j], acc[i][j]);
    }
#pragma unroll
    for (int i = 0; i < 8; ++i) {
      float4 v;
      v.x = fmaxf(fmaf(acc[i][0], a2r[i], d2r[i]), 0.f);
      v.y = fmaxf(fmaf(acc[i][1], a2r[i], d2r[i]), 0.f);
      v.z = fmaxf(fmaf(acc[i][2], a2r[i], d2r[i]), 0.f);
      v.w = fmaxf(fmaf(acc[i][3], a2r[i], d2r[i]), 0.f);
      *reinterpret_cast<float4*>(&X2s[(tmA * 8 + i) * 68 + tcA * 4]) = v;
    }
  }
  __syncthreads();   // also ensures all W2L reads done before W3c alias writes
  // phase B
  float acc3[8][8];
#pragma unroll
  for (int i = 0; i < 8; ++i)
#pragma unroll
    for (int j = 0; j < 8; ++j) acc3[i][j] = 0.f;
  for (int kc = 0; kc < 8; ++kc) {
#pragma unroll
    for (int q = 0; q < 4; ++q) {
      float4 w = *reinterpret_cast<const float4*>(&W3[(size_t)t * 128 + kc * 16 + q * 4]);
      W3c[(q * 4 + 0) * 256 + t] = w.x;
      W3c[(q * 4 + 1) * 256 + t] = w.y;
      W3c[(q * 4 + 2) * 256 + t] = w.z;
      W3c[(q * 4 + 3) * 256 + t] = w.w;
    }
    __syncthreads();
#pragma unroll
    for (int kk = 0; kk < 16; ++kk) {
      const float4* ap = reinterpret_cast<const float4*>(&W3c[kk * 256 + tm3 * 8]);
      float4 a0 = ap[0], a4 = ap[1];
      const float4* bp = reinterpret_cast<const float4*>(&X2s[(kc * 16 + kk) * 68 + tcol * 8]);
      float4 b0 = bp[0], b4 = bp[1];
      const float av[8] = {a0.x, a0.y, a0.z, a0.w, a4.x, a4.y, a4.z, a4.w};
      const float bw[8] = {b0.x, b0.y, b0.z, b0.w, b4.x, b4.y, b4.z, b4.w};
#pragma unroll
      for (int i = 0; i < 8; ++i)
#pragma unroll
        for (int j = 0; j < 8; ++j) acc3[i][j] = fmaf(av[i], bw[j], acc3[i][j]);
    }
    __syncthreads();
  }
  // epilogue: BN3 affine, max over 16-col groups (pair of lanes tcol, tcol^1), relu, store
#pragma unroll
  for (int i = 0; i < 8; ++i) {
    float mx = -__builtin_inff();
#pragma unroll
    for (int j = 0; j < 8; ++j) {
      float v = fmaf(acc3[i][j], a3r[i], d3r[i]);
      mx = fmaxf(mx, v);
    }
    float o = __shfl_xor(mx, 32, 64);
    mx = fmaxf(mx, o);
    if ((tcol & 1) == 0) {
      int g = tcol >> 1;
      int bs = ch * 4 + g;
      int b = bs / S_;
      int s = bs - b * S_;
      out1[((size_t)(b * 256 + tm3 * 8 + i)) * S_ + s] = fmaxf(mx, 0.f);
    }
  }
}

__global__ void diag_kernel(float* out, float v) {
  if (threadIdx.x == 0 && blockIdx.x == 0) out[0] = v;
}

extern "C" void kernel_launch(void* const* d_in, const int* in_sizes, int n_in,
                              void* d_out, int out_size, void* d_ws, size_t ws_size,
                              hipStream_t stream) {
  const float* xy  = (const float*)d_in[0];
  const float* fea = (const float*)d_in[1];
  const float* W1  = (const float*)d_in[2];
  const float* b1  = (const float*)d_in[3];
  const float* g1  = (const float*)d_in[4];
  const float* be1 = (const float*)d_in[5];
  const float* W2  = (const float*)d_in[6];
  const float* b2  = (const float*)d_in[7];   // folded via mu2' centering
  const float* g2  = (const float*)d_in[8];
  const float* be2 = (const float*)d_in[9];
  const float* W3  = (const float*)d_in[10];
  const float* b3  = (const float*)d_in[11];  // folded via mu3' centering
  const float* g3  = (const float*)d_in[12];
  const float* be3 = (const float*)d_in[13];
  (void)b2; (void)b3;
  float* out = (float*)d_out;
  float* out1 = out + B_ * 2 * S_;

  char* w = (char*)d_ws;
  size_t off = 0;
  auto take = [&](size_t bytes) -> void* {
    void* p = w + off;
    off += (bytes + 255) & ~(size_t)255;
    return p;
  };
  int*    fps_idx = (int*)take((size_t)B_ * S_ * 4);
  float*  new_xyz = (float*)take((size_t)B_ * S_ * 2 * 4);
  int*    knn_sel = (int*)take((size_t)NF_ * 4);
  float*  P       = (float*)take((size_t)B_ * N_ * 64 * 4);   // 8.4 MB
  float*  Y1      = (float*)take((size_t)64 * NF_ * 4);       // 67.2 MB
  double* Sy1     = (double*)take(64 * 8);
  double* var1r   = (double*)take(64 * 8);
  float*  A1      = (float*)take(64 * 4);
  float*  Bc1     = (float*)take(64 * 4);
  double* S1      = (double*)take(64 * 8);
  double* mu2p    = (double*)take(128 * 8);
  float*  var2p   = (float*)take((size_t)512 * 128 * 4);
  double* var2r   = (double*)take(128 * 8);
  float*  A2      = (float*)take(128 * 4);
  float*  D2      = (float*)take(128 * 4);
  float*  s2p     = (float*)take((size_t)512 * 128 * 4);
  double* S2      = (double*)take(128 * 8);
  double* mu3p    = (double*)take(256 * 8);
  float*  var3p   = (float*)take((size_t)256 * 256 * 4);
  double* var3r   = (double*)take(256 * 8);
  float*  A3      = (float*)take(256 * 4);
  float*  D3      = (float*)take(256 * 4);

  if (off > ws_size) {  // diagnostic: encode available MB in out[0]
    diag_kernel<<<1, 64, 0, stream>>>(out, (float)(ws_size >> 20));
    return;
  }

  fps_kernel<<<B_, 256, 0, stream>>>(xy, fps_idx, new_xyz, out);
  knn_kernel<<<dim3((S_ + 255) / 256, B_), 256, 0, stream>>>(xy, fps_idx, knn_sel);
  pk_kernel<<<B_ * 32, 256, 0, stream>>>(fea, W1, P);
  yk1_kernel<<<NF_ / 256, 256, 0, stream>>>(xy, knn_sel, new_xyz, P, W1, b1, Y1);

  rowsum_kernel<false><<<64, 1024, 0, stream>>>(Y1, nullptr, nullptr, Sy1);
  rowvar_kernel<<<64, 1024, 0, stream>>>(Y1, Sy1, var1r);
  absch_kernel<<<1, 64, 0, stream>>>(Sy1, var1r, g1, be1, A1, Bc1, 64, 1);
  rowsum_kernel<true><<<64, 1024, 0, stream>>>(Y1, A1, Bc1, S1);

  meanlin_kernel<<<1, 128, 0, stream>>>(W2, S1, mu2p, 128, 64);
  pass2_kernel<0><<<512, 256, 0, stream>>>(Y1, W2, A1, Bc1, mu2p, nullptr, nullptr, var2p);
  red_kernel<<<1, 128, 0, stream>>>(var2p, var2r, 512, 128);
  absch_kernel<<<1, 128, 0, stream>>>(mu2p, var2r, g2, be2, A2, D2, 128, 0);

  pass2_kernel<1><<<512, 256, 0, stream>>>(Y1, W2, A1, Bc1, nullptr, A2, D2, s2p);
  red_kernel<<<1, 128, 0, stream>>>(s2p, S2, 512, 128);
  meanlin_kernel<<<1, 256, 0, stream>>>(W3, S2, mu3p, 256, 128);

  var3_kernel<<<256, 256, 0, stream>>>(Y1, W2, W3, A1, Bc1, A2, D2, mu3p, var3p);
  red_kernel<<<1, 256, 0, stream>>>(var3p, var3r, 256, 256);
  absch_kernel<<<1, 256, 0, stream>>>(mu3p, var3r, g3, be3, A3, D3, 256, 0);

  final_kernel<<<NCH_, 256, 0, stream>>>(Y1, W2, W3, A1, Bc1, A2, D2, A3, D3, out1);
}

// Round 3
// 3803.015 us; speedup vs baseline: 1.2130x; 1.2130x over previous
//
#include <hip/hip_runtime.h>
#include <math.h>

#define B_   16
#define N_   2048
#define S_   1025
#define K_   16
#define EMB_ 64
#define NF_  (B_ * S_ * K_)   // 262400
#define NCH_ (NF_ / 64)       // 4100 column-chunks of 64

// ---------------- FPS: one block (512 thr) per batch, fp64-exact distances ----------------
__global__ __launch_bounds__(512) void fps_kernel(const float* __restrict__ xy,
                                                  int* __restrict__ fps_idx,
                                                  float* __restrict__ new_xyz,
                                                  float* __restrict__ out0) {
  const int b = blockIdx.x;
  const int tid = threadIdx.x;
  __shared__ float2 lxy[N_];
  __shared__ double bv[2][8];
  __shared__ int bi[2][8];
  const float* xb = xy + (size_t)b * 2 * N_;
  float px[4], py[4];
  double dist[4];
#pragma unroll
  for (int j = 0; j < 4; ++j) {
    int p = tid + 512 * j;
    float x = xb[p];
    float y = xb[N_ + p];
    lxy[p] = make_float2(x, y);
    px[j] = x; py[j] = y;
    dist[j] = __builtin_inf();
  }
  __syncthreads();
  int cur = 0;
  const int lane = tid & 63, wv = tid >> 6;
  for (int t = 0; t < S_; ++t) {
    if (tid == 0) {
      fps_idx[b * S_ + t] = cur;
      float2 c = lxy[cur];
      new_xyz[(b * S_ + t) * 2 + 0] = c.x;
      new_xyz[(b * S_ + t) * 2 + 1] = c.y;
      out0[b * 2 * S_ + t] = c.x;
      out0[b * 2 * S_ + S_ + t] = c.y;
    }
    float2 c = lxy[cur];
    const double cx = (double)c.x, cy = (double)c.y;
    double best = -__builtin_inf();
    int bidx = 0x7fffffff;
#pragma unroll
    for (int j = 0; j < 4; ++j) {
      double dx = (double)px[j] - cx;
      double dy = (double)py[j] - cy;
      double d = dx * dx + dy * dy;     // exact products in fp64 for fp32 inputs
      d = (d < dist[j]) ? d : dist[j];
      dist[j] = d;
      if (d > best) { best = d; bidx = tid + 512 * j; }  // ascending idx -> strict > keeps lowest
    }
#pragma unroll
    for (int m = 1; m < 64; m <<= 1) {
      double v2 = __shfl_xor(best, m, 64);
      int i2 = __shfl_xor(bidx, m, 64);
      if (v2 > best || (v2 == best && i2 < bidx)) { best = v2; bidx = i2; }
    }
    if (lane == 0) { bv[t & 1][wv] = best; bi[t & 1][wv] = bidx; }
    __syncthreads();   // single barrier: double-buffered bv/bi removes the WAR barrier
    double v = bv[t & 1][0]; int vi = bi[t & 1][0];
#pragma unroll
    for (int w = 1; w < 8; ++w) {
      double v2 = bv[t & 1][w]; int i2 = bi[t & 1][w];
      if (v2 > v || (v2 == v && i2 < vi)) { v = v2; vi = i2; }
    }
    cur = vi;
  }
}

// ---------------- KNN fp64-exact, 8 lanes per query point, register bitonic merges ----------------
// Lex order (d, idx) == stable top_k tie semantics. Downstream is k-max-pool -> only the SET matters.
__global__ __launch_bounds__(256) void knn_kernel(const float* __restrict__ xy,
                                                  const int* __restrict__ fps_idx,
                                                  int* __restrict__ knn_sel) {
  const int b = blockIdx.y;
  __shared__ float2 lxy[N_];    // 16 KB
  __shared__ double lsq[N_];    // 16 KB
  const float* xb = xy + (size_t)b * 2 * N_;
  for (int p = threadIdx.x; p < N_; p += 256) {
    float x = xb[p], y = xb[N_ + p];
    lxy[p] = make_float2(x, y);
    lsq[p] = (double)x * (double)x + (double)y * (double)y;  // exact
  }
  __syncthreads();
  const int t = threadIdx.x;
  const int s = blockIdx.x * 32 + (t >> 3);
  if (s >= S_) return;          // whole 8-lane group shares s -> uniform exit
  const int oct = t & 7;
  const int p0 = fps_idx[b * S_ + s];
  float2 q = lxy[p0];
  const double xn = (double)q.x, yn = (double)q.y;
  const double sqn = lsq[p0];
  double d16[16];
  int i16[16];
#pragma unroll
  for (int j = 0; j < 16; ++j) { d16[j] = __builtin_inf(); i16[j] = 0x7fffffff; }
  const int mlo = oct * 256;
  for (int m0 = mlo; m0 < mlo + 256; m0 += 4) {
    double dd[4];
#pragma unroll
    for (int u = 0; u < 4; ++u) {
      float2 p = lxy[m0 + u];
      double dot = (double)p.x * xn + (double)p.y * yn;   // exact products -> fma == mul,mul,add
      dd[u] = (sqn - 2.0 * dot) + lsq[m0 + u];            // reference rounding order
    }
#pragma unroll
    for (int u = 0; u < 4; ++u) {
      if (dd[u] < d16[15]) {   // strict <: within ascending scan this is lex-correct
        double d = dd[u];
        int mi = m0 + u;
#pragma unroll
        for (int j = 15; j >= 1; --j) {
          bool shift = d < d16[j - 1];
          bool ins = d < d16[j];
          d16[j] = shift ? d16[j - 1] : (ins ? d : d16[j]);
          i16[j] = shift ? i16[j - 1] : (ins ? mi : i16[j]);
        }
        if (d < d16[0]) { d16[0] = d; i16[0] = mi; }
      }
    }
  }
  // 3 merge rounds across the 8-lane group (xor 1,2,4).
  // Half-cleaner: nd[i] = lexmin(a[i], rev_b[i]) -> k-smallest multiset, bitonic; then 4-stage sort.
#pragma unroll
  for (int w = 1; w <= 4; w <<= 1) {
    double nd[16]; int ni[16];
#pragma unroll
    for (int i = 0; i < 16; ++i) {
      double rd = __shfl_xor(d16[15 - i], w, 64);
      int ri = __shfl_xor(i16[15 - i], w, 64);
      bool takeR = (rd < d16[i]) || (rd == d16[i] && ri < i16[i]);
      nd[i] = takeR ? rd : d16[i];
      ni[i] = takeR ? ri : i16[i];
    }
#pragma unroll
    for (int i = 0; i < 16; ++i) { d16[i] = nd[i]; i16[i] = ni[i]; }
    if (w < 4) {  // rounds 1,2 must leave sorted input for the next round; last round set-only
#pragma unroll
      for (int dstg = 8; dstg >= 1; dstg >>= 1) {
#pragma unroll
        for (int i = 0; i < 16; ++i) {
          if ((i & dstg) == 0) {
            int a = i, c = i + dstg;
            bool sw = (d16[a] > d16[c]) || (d16[a] == d16[c] && i16[a] > i16[c]);
            double tlo = sw ? d16[c] : d16[a];
            double thi = sw ? d16[a] : d16[c];
            int ulo = sw ? i16[c] : i16[a];
            int uhi = sw ? i16[a] : i16[c];
            d16[a] = tlo; d16[c] = thi; i16[a] = ulo; i16[c] = uhi;
          }
        }
      }
    }
  }
  if (oct == 0) {
    int* dst = knn_sel + ((size_t)b * S_ + s) * K_;
#pragma unroll
    for (int j = 0; j < 16; ++j) dst[j] = i16[j];
  }
}

// ---------------- P[b][pt][c] = sum_e W1[c][2+e] * fea[b][e][pt] ----------------
__global__ __launch_bounds__(256) void pk_kernel(const float* __restrict__ fea,
                                                 const float* __restrict__ W1,
                                                 float* __restrict__ P) {
  const int t = threadIdx.x;
  const int b = blockIdx.x >> 5;
  const int pt0 = (blockIdx.x & 31) << 6;
  __shared__ float W1L[64 * 64];   // [e][c]
  __shared__ float feaL[64 * 64];  // [e][pt]
#pragma unroll
  for (int p = 0; p < 16; ++p) {
    int idx = t + 256 * p;
    int c = idx >> 6, e = idx & 63;
    W1L[e * 64 + c] = W1[c * 66 + 2 + e];
    int r = (t >> 6) + 4 * p, cc = t & 63;
    feaL[r * 64 + cc] = fea[((size_t)b * 64 + r) * N_ + pt0 + cc];
  }
  __syncthreads();
  const int tpt = t & 15, tcq = t >> 4;
  float acc[4][4];
#pragma unroll
  for (int i = 0; i < 4; ++i)
#pragma unroll
    for (int j = 0; j < 4; ++j) acc[i][j] = 0.f;
  for (int e = 0; e < 64; ++e) {
    float4 a4 = *reinterpret_cast<const float4*>(&W1L[e * 64 + tcq * 4]);
    float4 b4 = *reinterpret_cast<const float4*>(&feaL[e * 64 + tpt * 4]);
    const float av[4] = {a4.x, a4.y, a4.z, a4.w};
    const float bvv[4] = {b4.x, b4.y, b4.z, b4.w};
#pragma unroll
    for (int i = 0; i < 4; ++i)
#pragma unroll
      for (int j = 0; j < 4; ++j) acc[i][j] = fmaf(av[i], bvv[j], acc[i][j]);
  }
#pragma unroll
  for (int j = 0; j < 4; ++j) {
    int pt = tpt * 4 + j;
    float4 v = {acc[0][j], acc[1][j], acc[2][j], acc[3][j]};
    *reinterpret_cast<float4*>(&P[((size_t)(b * N_ + pt0 + pt)) * 64 + tcq * 4]) = v;
  }
}

// ---------------- Y1[64][NF]: gather P + W1a*dxy + b1 ----------------
__global__ __launch_bounds__(256) void yk1_kernel(const float* __restrict__ xy,
                                                  const int* __restrict__ knn_sel,
                                                  const float* __restrict__ new_xyz,
                                                  const float* __restrict__ P,
                                                  const float* __restrict__ W1,
                                                  const float* __restrict__ b1,
                                                  float* __restrict__ Y1) {
  __shared__ float w0s[64], w1s[64], bbs[64];
  const int t = threadIdx.x;
  if (t < 64) { w0s[t] = W1[t * 66 + 0]; w1s[t] = W1[t * 66 + 1]; bbs[t] = b1[t]; }
  __syncthreads();
  const int n = blockIdx.x * 256 + t;
  const int bs = n >> 4;
  const int b = bs / S_;
  const int nbr = knn_sel[n];
  const float dx = xy[(size_t)b * 2 * N_ + nbr] - new_xyz[bs * 2 + 0];
  const float dy = xy[(size_t)b * 2 * N_ + N_ + nbr] - new_xyz[bs * 2 + 1];
  const float* prow = &P[((size_t)(b * N_ + nbr)) * 64];
  for (int c4 = 0; c4 < 64; c4 += 4) {
    float4 p4 = *reinterpret_cast<const float4*>(&prow[c4]);
    float v0 = p4.x + w0s[c4 + 0] * dx + w1s[c4 + 0] * dy + bbs[c4 + 0];
    float v1 = p4.y + w0s[c4 + 1] * dx + w1s[c4 + 1] * dy + bbs[c4 + 1];
    float v2 = p4.z + w0s[c4 + 2] * dx + w1s[c4 + 2] * dy + bbs[c4 + 2];
    float v3 = p4.w + w0s[c4 + 3] * dx + w1s[c4 + 3] * dy + bbs[c4 + 3];
    Y1[(size_t)(c4 + 0) * NF_ + n] = v0;
    Y1[(size_t)(c4 + 1) * NF_ + n] = v1;
    Y1[(size_t)(c4 + 2) * NF_ + n] = v2;
    Y1[(size_t)(c4 + 3) * NF_ + n] = v3;
  }
}

// ---------------- per-row sum (optionally affine+relu), double accumulators ----------------
template <bool AFF>
__global__ __launch_bounds__(1024) void rowsum_kernel(const float* __restrict__ Y,
                                                      const float* __restrict__ A,
                                                      const float* __restrict__ Bc,
                                                      double* __restrict__ out) {
  const int r = blockIdx.x;
  const float a = AFF ? A[r] : 0.f, c = AFF ? Bc[r] : 0.f;
  double s = 0.0;
  for (int i = threadIdx.x; i < NF_; i += 1024) {
    float v = Y[(size_t)r * NF_ + i];
    if (AFF) v = fmaxf(fmaf(v, a, c), 0.f);
    s += (double)v;
  }
  __shared__ double sh[1024];
  sh[threadIdx.x] = s;
  __syncthreads();
  for (int o = 512; o > 0; o >>= 1) {
    if (threadIdx.x < o) sh[threadIdx.x] += sh[threadIdx.x + o];
    __syncthreads();
  }
  if (threadIdx.x == 0) out[r] = sh[0];
}

// ---------------- per-row centered sumsq ----------------
__global__ __launch_bounds__(1024) void rowvar_kernel(const float* __restrict__ Y,
                                                      const double* __restrict__ sums,
                                                      double* __restrict__ out) {
  const int r = blockIdx.x;
  const double mu = sums[r] * (1.0 / NF_);
  double s = 0.0;
  for (int i = threadIdx.x; i < NF_; i += 1024) {
    double d = (double)Y[(size_t)r * NF_ + i] - mu;
    s += d * d;
  }
  __shared__ double sh[1024];
  sh[threadIdx.x] = s;
  __syncthreads();
  for (int o = 512; o > 0; o >>= 1) {
    if (threadIdx.x < o) sh[threadIdx.x] += sh[threadIdx.x + o];
    __syncthreads();
  }
  if (threadIdx.x == 0) out[r] = sh[0];
}

// ---------------- A = g*rsqrt(var+eps); D = be - A*mu ----------------
__global__ void absch_kernel(const double* __restrict__ muv, const double* __restrict__ varraw,
                             const float* __restrict__ g, const float* __restrict__ be,
                             float* __restrict__ A, float* __restrict__ D, int M, int mu_is_sum) {
  int m = threadIdx.x;
  if (m >= M) return;
  double mu = mu_is_sum ? muv[m] * (1.0 / NF_) : muv[m];
  double var = varraw[m] * (1.0 / NF_);
  double a = (double)g[m] / sqrt(var + 1e-5);
  A[m] = (float)a;
  D[m] = (float)((double)be[m] - a * mu);
}

// ---------------- mu[m] = dot(W[m,:K], S)/NF ----------------
__global__ void meanlin_kernel(const float* __restrict__ W, const double* __restrict__ S,
                               double* __restrict__ mu, int M, int K) {
  int m = threadIdx.x;
  if (m >= M) return;
  double acc = 0.0;
  for (int k = 0; k < K; ++k) acc += (double)W[m * K + k] * S[k];
  mu[m] = acc * (1.0 / NF_);
}

// ---------------- reduce partials [P][M] -> double[M] ----------------
__global__ void red_kernel(const float* __restrict__ parts, double* __restrict__ out, int P, int M) {
  int m = threadIdx.x;
  if (m >= M) return;
  double a = 0.0;
  for (int p = 0; p < P; ++p) a += (double)parts[(size_t)p * M + m];
  out[m] = a;
}

// ============ GEMM2 pass kernels: y2[128][64cols] per chunk, x1 from Y1 on the fly ============
template <int MODE>  // 0: accumulate (y2-mu2')^2 ; 1: accumulate relu(A2*y2+D2)
__global__ __launch_bounds__(256) void pass2_kernel(const float* __restrict__ Y1,
                                                    const float* __restrict__ W2,
                                                    const float* __restrict__ A1v,
                                                    const float* __restrict__ Bc1v,
                                                    const double* __restrict__ mu2p,
                                                    const float* __restrict__ A2v,
                                                    const float* __restrict__ D2v,
                                                    float* __restrict__ parts) {
  __shared__ float W2L[64 * 128];
  __shared__ float ab[128];
  __shared__ float vpart[16][128];
  const int t = threadIdx.x;
#pragma unroll
  for (int p = 0; p < 32; ++p) {
    int idx = t + 256 * p;
    int m = idx >> 6, k = idx & 63;
    W2L[k * 128 + m] = W2[m * 64 + k];
  }
  if (t < 64) { ab[t] = A1v[t]; ab[64 + t] = Bc1v[t]; }
  const int tmA = t >> 4, tcA = t & 15;
  float par0[8], par1[8], vacc[8];
#pragma unroll
  for (int i = 0; i < 8; ++i) {
    int m = tmA * 8 + i;
    if (MODE == 0) { par0[i] = (float)mu2p[m]; par1[i] = 0.f; }
    else { par0[i] = A2v[m]; par1[i] = D2v[m]; }
    vacc[i] = 0.f;
  }
  __syncthreads();
  for (int ch = blockIdx.x; ch < NCH_; ch += 512) {
    const size_t n0 = (size_t)ch * 64;
    float acc[8][4];
#pragma unroll
    for (int i = 0; i < 8; ++i)
#pragma unroll
      for (int j = 0; j < 4; ++j) acc[i][j] = 0.f;
#pragma unroll 2
    for (int k = 0; k < 64; ++k) {
      float4 y4 = *reinterpret_cast<const float4*>(&Y1[(size_t)k * NF_ + n0 + tcA * 4]);
      float a1 = ab[k], c1 = ab[64 + k];
      float bx[4];
      bx[0] = fmaxf(fmaf(y4.x, a1, c1), 0.f);
      bx[1] = fmaxf(fmaf(y4.y, a1, c1), 0.f);
      bx[2] = fmaxf(fmaf(y4.z, a1, c1), 0.f);
      bx[3] = fmaxf(fmaf(y4.w, a1, c1), 0.f);
      const float4* ap = reinterpret_cast<const float4*>(&W2L[k * 128 + tmA * 8]);
      float4 a0 = ap[0], a4 = ap[1];
      const float av[8] = {a0.x, a0.y, a0.z, a0.w, a4.x, a4.y, a4.z, a4.w};
#pragma unroll
      for (int i = 0; i < 8; ++i)
#pragma unroll
        for (int j = 0; j < 4; ++j) acc[i][j] = fmaf(av[i], bx[j], acc[i][j]);
    }
#pragma unroll
    for (int i = 0; i < 8; ++i)
#pragma unroll
      for (int j = 0; j < 4; ++j) {
        if (MODE == 0) {
          float d = acc[i][j] - par0[i];
          vacc[i] = fmaf(d, d, vacc[i]);
        } else {
          vacc[i] += fmaxf(fmaf(acc[i][j], par0[i], par1[i]), 0.f);
        }
      }
  }
#pragma unroll
  for (int i = 0; i < 8; ++i) vpart[tcA][tmA * 8 + i] = vacc[i];
  __syncthreads();
  if (t < 128) {
    float s = 0.f;
    for (int q = 0; q < 16; ++q) s += vpart[q][t];
    parts[(size_t)blockIdx.x * 128 + t] = s;
  }
}

// ============ var3 pass: y3 = W3 * relu(A2*(W2*x1)+D2), accumulate (y3-mu3')^2 ============
__global__ __launch_bounds__(256) void var3_kernel(const float* __restrict__ Y1,
                                                   const float* __restrict__ W2,
                                                   const float* __restrict__ W3,
                                                   const float* __restrict__ A1v,
                                                   const float* __restrict__ Bc1v,
                                                   const float* __restrict__ A2v,
                                                   const float* __restrict__ D2v,
                                                   const double* __restrict__ mu3p,
                                                   float* __restrict__ parts) {
  __shared__ float W2L[64 * 128];     // persistent
  __shared__ float ab[128];
  __shared__ float X2s[128 * 68];
  __shared__ float W3c[16 * 256];
  __shared__ float vpart3[8][256];
  const int t = threadIdx.x;
#pragma unroll
  for (int p = 0; p < 32; ++p) {
    int idx = t + 256 * p;
    int m = idx >> 6, k = idx & 63;
    W2L[k * 128 + m] = W2[m * 64 + k];
  }
  if (t < 64) { ab[t] = A1v[t]; ab[64 + t] = Bc1v[t]; }
  const int tmA = t >> 4, tcA = t & 15;
  const int tm3 = t & 31, tcol = t >> 5;
  float a2r[8], d2r[8], mu3[8], vacc[8];
#pragma unroll
  for (int i = 0; i < 8; ++i) {
    a2r[i] = A2v[tmA * 8 + i];
    d2r[i] = D2v[tmA * 8 + i];
    mu3[i] = (float)mu3p[tm3 * 8 + i];
    vacc[i] = 0.f;
  }
  __syncthreads();
  for (int ch = blockIdx.x; ch < NCH_; ch += 256) {
    const size_t n0 = (size_t)ch * 64;
    {
      float acc[8][4];
#pragma unroll
      for (int i = 0; i < 8; ++i)
#pragma unroll
        for (int j = 0; j < 4; ++j) acc[i][j] = 0.f;
#pragma unroll 2
      for (int k = 0; k < 64; ++k) {
        float4 y4 = *reinterpret_cast<const float4*>(&Y1[(size_t)k * NF_ + n0 + tcA * 4]);
        float a1 = ab[k], c1 = ab[64 + k];
        float bx[4];
        bx[0] = fmaxf(fmaf(y4.x, a1, c1), 0.f);
        bx[1] = fmaxf(fmaf(y4.y, a1, c1), 0.f);
        bx[2] = fmaxf(fmaf(y4.z, a1, c1), 0.f);
        bx[3] = fmaxf(fmaf(y4.w, a1, c1), 0.f);
        const float4* ap = reinterpret_cast<const float4*>(&W2L[k * 128 + tmA * 8]);
        float4 a0 = ap[0], a4 = ap[1];
        const float av[8] = {a0.x, a0.y, a0.z, a0.w, a4.x, a4.y, a4.z, a4.w};
#pragma unroll
        for (int i = 0; i < 8; ++i)
#pragma unroll
          for (int j = 0; j < 4; ++j) acc[i][j] = fmaf(av[i], bx[j], acc[i][j]);
      }
#pragma unroll
      for (int i = 0; i < 8; ++i) {
        float4 v;
        v.x = fmaxf(fmaf(acc[i][0], a2r[i], d2r[i]), 0.f);
        v.y = fmaxf(fmaf(acc[i][1], a2r[i], d2r[i]), 0.f);
        v.z = fmaxf(fmaf(acc[i][2], a2r[i], d2r[i]), 0.f);
        v.w = fmaxf(fmaf(acc[i][3], a2r[i], d2r[i]), 0.f);
        *reinterpret_cast<float4*>(&X2s[(tmA * 8 + i) * 68 + tcA * 4]) = v;
      }
    }
    __syncthreads();
    float acc3[8][8];
#pragma unroll
    for (int i = 0; i < 8; ++i)
#pragma unroll
      for (int j = 0; j < 8; ++j) acc3[i][j] = 0.f;
    for (int kc = 0; kc < 8; ++kc) {
#pragma unroll
      for (int q = 0; q < 4; ++q) {
        float4 w = *reinterpret_cast<const float4*>(&W3[(size_t)t * 128 + kc * 16 + q * 4]);
        W3c[(q * 4 + 0) * 256 + t] = w.x;
        W3c[(q * 4 + 1) * 256 + t] = w.y;
        W3c[(q * 4 + 2) * 256 + t] = w.z;
        W3c[(q * 4 + 3) * 256 + t] = w.w;
      }
      __syncthreads();
#pragma unroll
      for (int kk = 0; kk < 16; ++kk) {
        const float4* ap = reinterpret_cast<const float4*>(&W3c[kk * 256 + tm3 * 8]);
        float4 a0 = ap[0], a4 = ap[1];
        const float4* bp = reinterpret_cast<const float4*>(&X2s[(kc * 16 + kk) * 68 + tcol * 8]);
        float4 b0 = bp[0], b4 = bp[1];
        const float av[8] = {a0.x, a0.y, a0.z, a0.w, a4.x, a4.y, a4.z, a4.w};
        const float bw[8] = {b0.x, b0.y, b0.z, b0.w, b4.x, b4.y, b4.z, b4.w};
#pragma unroll
        for (int i = 0; i < 8; ++i)
#pragma unroll
          for (int j = 0; j < 8; ++j) acc3[i][j] = fmaf(av[i], bw[j], acc3[i][j]);
      }
      __syncthreads();
    }
#pragma unroll
    for (int i = 0; i < 8; ++i)
#pragma unroll
      for (int j = 0; j < 8; ++j) {
        float d = acc3[i][j] - mu3[i];
        vacc[i] = fmaf(d, d, vacc[i]);
      }
    __syncthreads();
  }
#pragma unroll
  for (int i = 0; i < 8; ++i) vpart3[tcol][tm3 * 8 + i] = vacc[i];
  __syncthreads();
  {
    float s = 0.f;
    for (int q = 0; q < 8; ++q) s += vpart3[q][t];
    parts[(size_t)blockIdx.x * 256 + t] = s;
  }
}

// ============ final pass: GEMM2 -> BN -> relu -> GEMM3 -> BN -> max over k -> relu -> out1 ============
__global__ __launch_bounds__(256) void final_kernel(const float* __restrict__ Y1,
                                                    const float* __restrict__ W2,
                                                    const float* __restrict__ W3,
                                                    const float* __restrict__ A1v,
                                                    const float* __restrict__ Bc1v,
                                                    const float* __restrict__ A2v,
                                                    const float* __restrict__ D2v,
                                                    const float* __restrict__ A3v,
                                                    const float* __restrict__ D3v,
                                                    float* __restrict__ out1) {
  __shared__ float W2L[64 * 128];   // aliased as W3c in phase B
  __shared__ float ab[128];
  __shared__ float X2s[128 * 68];
  float* W3c = W2L;
  const int t = threadIdx.x;
#pragma unroll
  for (int p = 0; p < 32; ++p) {
    int idx = t + 256 * p;
    int m = idx >> 6, k = idx & 63;
    W2L[k * 128 + m] = W2[m * 64 + k];
  }
  if (t < 64) { ab[t] = A1v[t]; ab[64 + t] = Bc1v[t]; }
  const int tmA = t >> 4, tcA = t & 15;
  const int tm3 = t & 31, tcol = t >> 5;
  float a2r[8], d2r[8], a3r[8], d3r[8];
#pragma unroll
  for (int i = 0; i < 8; ++i) {
    a2r[i] = A2v[tmA * 8 + i];
    d2r[i] = D2v[tmA * 8 + i];
    a3r[i] = A3v[tm3 * 8 + i];
    d3r[i] = D3v[tm3 * 8 + i];
  }
  __syncthreads();
  const int ch = blockIdx.x;
  const size_t n0 = (size_t)ch * 64;
  {
    float acc[8][4];
#pragma unroll
    for (int i = 0; i < 8; ++i)
#pragma unroll
      for (int j = 0; j < 4; ++j) acc[i][j] = 0.f;
#pragma unroll 2
    for (int k = 0; k < 64; ++k) {
      float4 y4 = *reinterpret_cast<const float4*>(&Y1[(size_t)k * NF_ + n0 + tcA * 4]);
      float a1 = ab[k], c1 = ab[64 + k];
      float bx[4];
      bx[0] = fmaxf(fmaf(y4.x, a1, c1), 0.f);
      bx[1] = fmaxf(fmaf(y4.y, a1, c1), 0.f);
      bx[2] = fmaxf(fmaf(y4.z, a1, c1), 0.f);
      bx[3] = fmaxf(fmaf(y4.w, a1, c1), 0.f);
      const float4* ap = reinterpret_cast<const float4*>(&W2L[k * 128 + tmA * 8]);
      float4 a0 = ap[0], a4 = ap[1];
      const float av[8] = {a0.x, a0.y, a0.z, a0.w, a4.x, a4.y, a4.z, a4.w};
#pragma unroll
      for (int i = 0; i < 8; ++i)
#pragma unroll
        for (int j = 0; j < 4; ++j) acc[i][j] = fmaf(av[i], bx[j], acc[i][j]);
    }
#pragma unroll
    for (int i = 0; i < 8; ++i) {
      float4 v;
      v.x = fmaxf(fmaf(acc[i][0], a2r[i], d2r[i]), 0.f);
      v.y = fmaxf(fmaf(acc[i][1], a2r[i], d2r[i]), 0.f);
      v.z = fmaxf(fmaf(acc[i][2], a2r[i], d2r[i]), 0.f);
      v.w = fmaxf(fmaf(acc[i][3], a2r[i], d2r[i]), 0.f);
      *reinterpret_cast<float4*>(&X2s[(tmA * 8 + i) * 68 + tcA * 4]) = v;
    }
  }
  __syncthreads();
  float acc3[8][8];
#pragma unroll
  for (int i = 0; i < 8; ++i)
#pragma unroll
    for (int j = 0; j < 8; ++j) acc3[i][j] = 0.f;
  for (int kc = 0; kc < 8; ++kc) {
#pragma unroll
    for (int q = 0; q < 4; ++q) {
      float4 w = *reinterpret_cast<const float4*>(&W3[(size_t)t * 128 + kc * 16 + q * 4]);
      W3c[(q * 4 + 0) * 256 + t] = w.x;
      W3c[(q * 4 + 1) * 256 + t] = w.y;
      W3c[(q * 4 + 2) * 256 + t] = w.z;
      W3c[(q * 4 + 3) * 256 + t] = w.w;
    }
    __syncthreads();
#pragma unroll
    for (int kk = 0; kk < 16; ++kk) {
      const float4* ap = reinterpret_cast<const float4*>(&W3c[kk * 256 + tm3 * 8]);
      float4 a0 = ap[0], a4 = ap[1];
      const float4* bp = reinterpret_cast<const float4*>(&X2s[(kc * 16 + kk) * 68 + tcol * 8]);
      float4 b0 = bp[0], b4 = bp[1];
      const float av[8] = {a0.x, a0.y, a0.z, a0.w, a4.x, a4.y, a4.z, a4.w};
      const float bw[8] = {b0.x, b0.y, b0.z, b0.w, b4.x, b4.y, b4.z, b4.w};
#pragma unroll
      for (int i = 0; i < 8; ++i)
#pragma unroll
        for (int j = 0; j < 8; ++j) acc3[i][j] = fmaf(av[i], bw[j], acc3[i][j]);
    }
    __syncthreads();
  }
#pragma unroll
  for (int i = 0; i < 8; ++i) {
    float mx = -__builtin_inff();
#pragma unroll
    for (int j = 0; j < 8; ++j) {
      float v = fmaf(acc3[i][j], a3r[i], d3r[i]);
      mx = fmaxf(mx, v);
    }
    float o = __shfl_xor(mx, 32, 64);
    mx = fmaxf(mx, o);
    if ((tcol & 1) == 0) {
      int g = tcol >> 1;
      int bs = ch * 4 + g;
      int b = bs / S_;
      int s = bs - b * S_;
      out1[((size_t)(b * 256 + tm3 * 8 + i)) * S_ + s] = fmaxf(mx, 0.f);
    }
  }
}

__global__ void diag_kernel(float* out, float v) {
  if (threadIdx.x == 0 && blockIdx.x == 0) out[0] = v;
}

extern "C" void kernel_launch(void* const* d_in, const int* in_sizes, int n_in,
                              void* d_out, int out_size, void* d_ws, size_t ws_size,
                              hipStream_t stream) {
  const float* xy  = (const float*)d_in[0];
  const float* fea = (const float*)d_in[1];
  const float* W1  = (const float*)d_in[2];
  const float* b1  = (const float*)d_in[3];
  const float* g1  = (const float*)d_in[4];
  const float* be1 = (const float*)d_in[5];
  const float* W2  = (const float*)d_in[6];
  const float* b2  = (const float*)d_in[7];
  const float* g2  = (const float*)d_in[8];
  const float* be2 = (const float*)d_in[9];
  const float* W3  = (const float*)d_in[10];
  const float* b3  = (const float*)d_in[11];
  const float* g3  = (const float*)d_in[12];
  const float* be3 = (const float*)d_in[13];
  (void)b2; (void)b3;
  float* out = (float*)d_out;
  float* out1 = out + B_ * 2 * S_;

  char* w = (char*)d_ws;
  size_t off = 0;
  auto take = [&](size_t bytes) -> void* {
    void* p = w + off;
    off += (bytes + 255) & ~(size_t)255;
    return p;
  };
  int*    fps_idx = (int*)take((size_t)B_ * S_ * 4);
  float*  new_xyz = (float*)take((size_t)B_ * S_ * 2 * 4);
  int*    knn_sel = (int*)take((size_t)NF_ * 4);
  float*  P       = (float*)take((size_t)B_ * N_ * 64 * 4);   // 8.4 MB
  float*  Y1      = (float*)take((size_t)64 * NF_ * 4);       // 67.2 MB
  double* Sy1     = (double*)take(64 * 8);
  double* var1r   = (double*)take(64 * 8);
  float*  A1      = (float*)take(64 * 4);
  float*  Bc1     = (float*)take(64 * 4);
  double* S1      = (double*)take(64 * 8);
  double* mu2p    = (double*)take(128 * 8);
  float*  var2p   = (float*)take((size_t)512 * 128 * 4);
  double* var2r   = (double*)take(128 * 8);
  float*  A2      = (float*)take(128 * 4);
  float*  D2      = (float*)take(128 * 4);
  float*  s2p     = (float*)take((size_t)512 * 128 * 4);
  double* S2      = (double*)take(128 * 8);
  double* mu3p    = (double*)take(256 * 8);
  float*  var3p   = (float*)take((size_t)256 * 256 * 4);
  double* var3r   = (double*)take(256 * 8);
  float*  A3      = (float*)take(256 * 4);
  float*  D3      = (float*)take(256 * 4);

  if (off > ws_size) {
    diag_kernel<<<1, 64, 0, stream>>>(out, (float)(ws_size >> 20));
    return;
  }

  fps_kernel<<<B_, 512, 0, stream>>>(xy, fps_idx, new_xyz, out);
  knn_kernel<<<dim3((S_ + 31) / 32, B_), 256, 0, stream>>>(xy, fps_idx, knn_sel);
  pk_kernel<<<B_ * 32, 256, 0, stream>>>(fea, W1, P);
  yk1_kernel<<<NF_ / 256, 256, 0, stream>>>(xy, knn_sel, new_xyz, P, W1, b1, Y1);

  rowsum_kernel<false><<<64, 1024, 0, stream>>>(Y1, nullptr, nullptr, Sy1);
  rowvar_kernel<<<64, 1024, 0, stream>>>(Y1, Sy1, var1r);
  absch_kernel<<<1, 64, 0, stream>>>(Sy1, var1r, g1, be1, A1, Bc1, 64, 1);
  rowsum_kernel<true><<<64, 1024, 0, stream>>>(Y1, A1, Bc1, S1);

  meanlin_kernel<<<1, 128, 0, stream>>>(W2, S1, mu2p, 128, 64);
  pass2_kernel<0><<<512, 256, 0, stream>>>(Y1, W2, A1, Bc1, mu2p, nullptr, nullptr, var2p);
  red_kernel<<<1, 128, 0, stream>>>(var2p, var2r, 512, 128);
  absch_kernel<<<1, 128, 0, stream>>>(mu2p, var2r, g2, be2, A2, D2, 128, 0);

  pass2_kernel<1><<<512, 256, 0, stream>>>(Y1, W2, A1, Bc1, nullptr, A2, D2, s2p);
  red_kernel<<<1, 128, 0, stream>>>(s2p, S2, 512, 128);
  meanlin_kernel<<<1, 256, 0, stream>>>(W3, S2, mu3p, 256, 128);

  var3_kernel<<<256, 256, 0, stream>>>(Y1, W2, W3, A1, Bc1, A2, D2, mu3p, var3p);
  red_kernel<<<1, 256, 0, stream>>>(var3p, var3r, 256, 256);
  absch_kernel<<<1, 256, 0, stream>>>(mu3p, var3r, g3, be3, A3, D3, 256, 0);

  final_kernel<<<NCH_, 256, 0, stream>>>(Y1, W2, W3, A1, Bc1, A2, D2, A3, D3, out1);
}

// Round 4
// 3349.500 us; speedup vs baseline: 1.3773x; 1.1354x over previous
//
#include <hip/hip_runtime.h>
#include <math.h>

#define B_   16
#define N_   2048
#define S_   1025
#define K_   16
#define EMB_ 64
#define NF_  (B_ * S_ * K_)   // 262400
#define NCH_ (NF_ / 64)       // 4100 column-chunks of 64

// ---------------- FPS: ONE WAVE (64 thr) per batch; no barriers, no cross-wave LDS reduce ----
// Lane l owns contiguous points [l*32, l*32+32). fp64-exact distances (contraction-immune for
// fp32 inputs: dx^2, dy^2 are exact products; single rounding at the add).
// Argmax = fp64 value-max butterfly (exact) -> per-lane equality scan for FIRST local match ->
// ballot+ffs for FIRST lane  == np.argmax lowest-index tie-break.
__global__ __launch_bounds__(64) void fps_kernel(const float* __restrict__ xy,
                                                 int* __restrict__ fps_idx,
                                                 float* __restrict__ new_xyz,
                                                 float* __restrict__ out0) {
  const int b = blockIdx.x;
  const int lane = threadIdx.x;   // 0..63
  __shared__ float2 lxy[N_];      // 16 KB
  const float* xb = xy + (size_t)b * 2 * N_;
  float px[32], py[32];
  double dist[32];
#pragma unroll
  for (int j = 0; j < 32; ++j) {
    int p = lane * 32 + j;
    float x = xb[p], y = xb[N_ + p];
    lxy[p] = make_float2(x, y);
    px[j] = x; py[j] = y;
    dist[j] = __builtin_inf();
  }
  __syncthreads();   // single wave: essentially free; orders LDS writes vs reads
  int cur = 0;
  for (int t = 0; t < S_; ++t) {
    if (lane == 0) {
      fps_idx[b * S_ + t] = cur;
      float2 c = lxy[cur];
      new_xyz[(b * S_ + t) * 2 + 0] = c.x;
      new_xyz[(b * S_ + t) * 2 + 1] = c.y;
      out0[b * 2 * S_ + t] = c.x;
      out0[b * 2 * S_ + S_ + t] = c.y;
    }
    float2 c = lxy[cur];
    const double cx = (double)c.x, cy = (double)c.y;
    double lmax = -__builtin_inf();
#pragma unroll
    for (int j = 0; j < 32; ++j) {
      double dx = (double)px[j] - cx;
      double dy = (double)py[j] - cy;
      double d = dx * dx + dy * dy;          // exact products; one rounding
      double nd = fmin(dist[j], d);
      dist[j] = nd;
      lmax = fmax(lmax, nd);
    }
    // exact value-max across wave
    double g = lmax;
#pragma unroll
    for (int m = 1; m < 64; m <<= 1) g = fmax(g, __shfl_xor(g, m, 64));
    // first local index equal to g (descending scan keeps lowest j)
    int lf = 64;
#pragma unroll
    for (int j = 31; j >= 0; --j)
      if (dist[j] == g) lf = j;
    int gidx = (lf < 32) ? (lane * 32 + lf) : 0x7fffffff;
    unsigned long long mask = __ballot(lf < 32);
    int first = __ffsll(mask) - 1;           // lowest lane with a hit (mask != 0 guaranteed)
    cur = __shfl(gidx, first, 64);
  }
}

// ---------------- KNN fp64-exact, 8 lanes per query point, register bitonic merges ----------------
// Lex order (d, idx) == stable top_k tie semantics. Downstream is k-max-pool -> only the SET matters.
__global__ __launch_bounds__(256) void knn_kernel(const float* __restrict__ xy,
                                                  const int* __restrict__ fps_idx,
                                                  int* __restrict__ knn_sel) {
  const int b = blockIdx.y;
  __shared__ float2 lxy[N_];    // 16 KB
  __shared__ double lsq[N_];    // 16 KB
  const float* xb = xy + (size_t)b * 2 * N_;
  for (int p = threadIdx.x; p < N_; p += 256) {
    float x = xb[p], y = xb[N_ + p];
    lxy[p] = make_float2(x, y);
    lsq[p] = (double)x * (double)x + (double)y * (double)y;  // exact
  }
  __syncthreads();
  const int t = threadIdx.x;
  const int s = blockIdx.x * 32 + (t >> 3);
  if (s >= S_) return;          // whole 8-lane group shares s -> uniform exit
  const int oct = t & 7;
  const int p0 = fps_idx[b * S_ + s];
  float2 q = lxy[p0];
  const double xn = (double)q.x, yn = (double)q.y;
  const double sqn = lsq[p0];
  double d16[16];
  int i16[16];
#pragma unroll
  for (int j = 0; j < 16; ++j) { d16[j] = __builtin_inf(); i16[j] = 0x7fffffff; }
  const int mlo = oct * 256;
  for (int m0 = mlo; m0 < mlo + 256; m0 += 4) {
    double dd[4];
#pragma unroll
    for (int u = 0; u < 4; ++u) {
      float2 p = lxy[m0 + u];
      double dot = (double)p.x * xn + (double)p.y * yn;   // exact products -> fma == mul,mul,add
      dd[u] = (sqn - 2.0 * dot) + lsq[m0 + u];            // reference rounding order
    }
#pragma unroll
    for (int u = 0; u < 4; ++u) {
      if (dd[u] < d16[15]) {   // strict <: within ascending scan this is lex-correct
        double d = dd[u];
        int mi = m0 + u;
#pragma unroll
        for (int j = 15; j >= 1; --j) {
          bool shift = d < d16[j - 1];
          bool ins = d < d16[j];
          d16[j] = shift ? d16[j - 1] : (ins ? d : d16[j]);
          i16[j] = shift ? i16[j - 1] : (ins ? mi : i16[j]);
        }
        if (d < d16[0]) { d16[0] = d; i16[0] = mi; }
      }
    }
  }
  // 3 merge rounds across the 8-lane group (xor 1,2,4).
#pragma unroll
  for (int w = 1; w <= 4; w <<= 1) {
    double nd[16]; int ni[16];
#pragma unroll
    for (int i = 0; i < 16; ++i) {
      double rd = __shfl_xor(d16[15 - i], w, 64);
      int ri = __shfl_xor(i16[15 - i], w, 64);
      bool takeR = (rd < d16[i]) || (rd == d16[i] && ri < i16[i]);
      nd[i] = takeR ? rd : d16[i];
      ni[i] = takeR ? ri : i16[i];
    }
#pragma unroll
    for (int i = 0; i < 16; ++i) { d16[i] = nd[i]; i16[i] = ni[i]; }
    if (w < 4) {
#pragma unroll
      for (int dstg = 8; dstg >= 1; dstg >>= 1) {
#pragma unroll
        for (int i = 0; i < 16; ++i) {
          if ((i & dstg) == 0) {
            int a = i, c = i + dstg;
            bool sw = (d16[a] > d16[c]) || (d16[a] == d16[c] && i16[a] > i16[c]);
            double tlo = sw ? d16[c] : d16[a];
            double thi = sw ? d16[a] : d16[c];
            int ulo = sw ? i16[c] : i16[a];
            int uhi = sw ? i16[a] : i16[c];
            d16[a] = tlo; d16[c] = thi; i16[a] = ulo; i16[c] = uhi;
          }
        }
      }
    }
  }
  if (oct == 0) {
    int* dst = knn_sel + ((size_t)b * S_ + s) * K_;
#pragma unroll
    for (int j = 0; j < 16; ++j) dst[j] = i16[j];
  }
}

// ---------------- P[b][pt][c] = sum_e W1[c][2+e] * fea[b][e][pt] ----------------
__global__ __launch_bounds__(256) void pk_kernel(const float* __restrict__ fea,
                                                 const float* __restrict__ W1,
                                                 float* __restrict__ P) {
  const int t = threadIdx.x;
  const int b = blockIdx.x >> 5;
  const int pt0 = (blockIdx.x & 31) << 6;
  __shared__ float W1L[64 * 64];   // [e][c]
  __shared__ float feaL[64 * 64];  // [e][pt]
#pragma unroll
  for (int p = 0; p < 16; ++p) {
    int idx = t + 256 * p;
    int c = idx >> 6, e = idx & 63;
    W1L[e * 64 + c] = W1[c * 66 + 2 + e];
    int r = (t >> 6) + 4 * p, cc = t & 63;
    feaL[r * 64 + cc] = fea[((size_t)b * 64 + r) * N_ + pt0 + cc];
  }
  __syncthreads();
  const int tpt = t & 15, tcq = t >> 4;
  float acc[4][4];
#pragma unroll
  for (int i = 0; i < 4; ++i)
#pragma unroll
    for (int j = 0; j < 4; ++j) acc[i][j] = 0.f;
  for (int e = 0; e < 64; ++e) {
    float4 a4 = *reinterpret_cast<const float4*>(&W1L[e * 64 + tcq * 4]);
    float4 b4 = *reinterpret_cast<const float4*>(&feaL[e * 64 + tpt * 4]);
    const float av[4] = {a4.x, a4.y, a4.z, a4.w};
    const float bvv[4] = {b4.x, b4.y, b4.z, b4.w};
#pragma unroll
    for (int i = 0; i < 4; ++i)
#pragma unroll
      for (int j = 0; j < 4; ++j) acc[i][j] = fmaf(av[i], bvv[j], acc[i][j]);
  }
#pragma unroll
  for (int j = 0; j < 4; ++j) {
    int pt = tpt * 4 + j;
    float4 v = {acc[0][j], acc[1][j], acc[2][j], acc[3][j]};
    *reinterpret_cast<float4*>(&P[((size_t)(b * N_ + pt0 + pt)) * 64 + tcq * 4]) = v;
  }
}

// ---------------- Y1[64][NF]: gather P + W1a*dxy + b1 ----------------
__global__ __launch_bounds__(256) void yk1_kernel(const float* __restrict__ xy,
                                                  const int* __restrict__ knn_sel,
                                                  const float* __restrict__ new_xyz,
                                                  const float* __restrict__ P,
                                                  const float* __restrict__ W1,
                                                  const float* __restrict__ b1,
                                                  float* __restrict__ Y1) {
  __shared__ float w0s[64], w1s[64], bbs[64];
  const int t = threadIdx.x;
  if (t < 64) { w0s[t] = W1[t * 66 + 0]; w1s[t] = W1[t * 66 + 1]; bbs[t] = b1[t]; }
  __syncthreads();
  const int n = blockIdx.x * 256 + t;
  const int bs = n >> 4;
  const int b = bs / S_;
  const int nbr = knn_sel[n];
  const float dx = xy[(size_t)b * 2 * N_ + nbr] - new_xyz[bs * 2 + 0];
  const float dy = xy[(size_t)b * 2 * N_ + N_ + nbr] - new_xyz[bs * 2 + 1];
  const float* prow = &P[((size_t)(b * N_ + nbr)) * 64];
  for (int c4 = 0; c4 < 64; c4 += 4) {
    float4 p4 = *reinterpret_cast<const float4*>(&prow[c4]);
    float v0 = p4.x + w0s[c4 + 0] * dx + w1s[c4 + 0] * dy + bbs[c4 + 0];
    float v1 = p4.y + w0s[c4 + 1] * dx + w1s[c4 + 1] * dy + bbs[c4 + 1];
    float v2 = p4.z + w0s[c4 + 2] * dx + w1s[c4 + 2] * dy + bbs[c4 + 2];
    float v3 = p4.w + w0s[c4 + 3] * dx + w1s[c4 + 3] * dy + bbs[c4 + 3];
    Y1[(size_t)(c4 + 0) * NF_ + n] = v0;
    Y1[(size_t)(c4 + 1) * NF_ + n] = v1;
    Y1[(size_t)(c4 + 2) * NF_ + n] = v2;
    Y1[(size_t)(c4 + 3) * NF_ + n] = v3;
  }
}

// ---------------- per-row sum (optionally affine+relu), double accumulators ----------------
template <bool AFF>
__global__ __launch_bounds__(1024) void rowsum_kernel(const float* __restrict__ Y,
                                                      const float* __restrict__ A,
                                                      const float* __restrict__ Bc,
                                                      double* __restrict__ out) {
  const int r = blockIdx.x;
  const float a = AFF ? A[r] : 0.f, c = AFF ? Bc[r] : 0.f;
  double s = 0.0;
  for (int i = threadIdx.x; i < NF_; i += 1024) {
    float v = Y[(size_t)r * NF_ + i];
    if (AFF) v = fmaxf(fmaf(v, a, c), 0.f);
    s += (double)v;
  }
  __shared__ double sh[1024];
  sh[threadIdx.x] = s;
  __syncthreads();
  for (int o = 512; o > 0; o >>= 1) {
    if (threadIdx.x < o) sh[threadIdx.x] += sh[threadIdx.x + o];
    __syncthreads();
  }
  if (threadIdx.x == 0) out[r] = sh[0];
}

// ---------------- per-row centered sumsq ----------------
__global__ __launch_bounds__(1024) void rowvar_kernel(const float* __restrict__ Y,
                                                      const double* __restrict__ sums,
                                                      double* __restrict__ out) {
  const int r = blockIdx.x;
  const double mu = sums[r] * (1.0 / NF_);
  double s = 0.0;
  for (int i = threadIdx.x; i < NF_; i += 1024) {
    double d = (double)Y[(size_t)r * NF_ + i] - mu;
    s += d * d;
  }
  __shared__ double sh[1024];
  sh[threadIdx.x] = s;
  __syncthreads();
  for (int o = 512; o > 0; o >>= 1) {
    if (threadIdx.x < o) sh[threadIdx.x] += sh[threadIdx.x + o];
    __syncthreads();
  }
  if (threadIdx.x == 0) out[r] = sh[0];
}

// ---------------- A = g*rsqrt(var+eps); D = be - A*mu ----------------
__global__ void absch_kernel(const double* __restrict__ muv, const double* __restrict__ varraw,
                             const float* __restrict__ g, const float* __restrict__ be,
                             float* __restrict__ A, float* __restrict__ D, int M, int mu_is_sum) {
  int m = threadIdx.x;
  if (m >= M) return;
  double mu = mu_is_sum ? muv[m] * (1.0 / NF_) : muv[m];
  double var = varraw[m] * (1.0 / NF_);
  double a = (double)g[m] / sqrt(var + 1e-5);
  A[m] = (float)a;
  D[m] = (float)((double)be[m] - a * mu);
}

// ---------------- mu[m] = dot(W[m,:K], S)/NF ----------------
__global__ void meanlin_kernel(const float* __restrict__ W, const double* __restrict__ S,
                               double* __restrict__ mu, int M, int K) {
  int m = threadIdx.x;
  if (m >= M) return;
  double acc = 0.0;
  for (int k = 0; k < K; ++k) acc += (double)W[m * K + k] * S[k];
  mu[m] = acc * (1.0 / NF_);
}

// ---------------- reduce partials [P][M] -> double[M] ----------------
__global__ void red_kernel(const float* __restrict__ parts, double* __restrict__ out, int P, int M) {
  int m = threadIdx.x;
  if (m >= M) return;
  double a = 0.0;
  for (int p = 0; p < P; ++p) a += (double)parts[(size_t)p * M + m];
  out[m] = a;
}

// ============ GEMM2 pass kernels: y2[128][64cols] per chunk, x1 from Y1 on the fly ============
template <int MODE>  // 0: accumulate (y2-mu2')^2 ; 1: accumulate relu(A2*y2+D2)
__global__ __launch_bounds__(256) void pass2_kernel(const float* __restrict__ Y1,
                                                    const float* __restrict__ W2,
                                                    const float* __restrict__ A1v,
                                                    const float* __restrict__ Bc1v,
                                                    const double* __restrict__ mu2p,
                                                    const float* __restrict__ A2v,
                                                    const float* __restrict__ D2v,
                                                    float* __restrict__ parts) {
  __shared__ float W2L[64 * 128];
  __shared__ float ab[128];
  __shared__ float vpart[16][128];
  const int t = threadIdx.x;
#pragma unroll
  for (int p = 0; p < 32; ++p) {
    int idx = t + 256 * p;
    int m = idx >> 6, k = idx & 63;
    W2L[k * 128 + m] = W2[m * 64 + k];
  }
  if (t < 64) { ab[t] = A1v[t]; ab[64 + t] = Bc1v[t]; }
  const int tmA = t >> 4, tcA = t & 15;
  float par0[8], par1[8], vacc[8];
#pragma unroll
  for (int i = 0; i < 8; ++i) {
    int m = tmA * 8 + i;
    if (MODE == 0) { par0[i] = (float)mu2p[m]; par1[i] = 0.f; }
    else { par0[i] = A2v[m]; par1[i] = D2v[m]; }
    vacc[i] = 0.f;
  }
  __syncthreads();
  for (int ch = blockIdx.x; ch < NCH_; ch += 512) {
    const size_t n0 = (size_t)ch * 64;
    float acc[8][4];
#pragma unroll
    for (int i = 0; i < 8; ++i)
#pragma unroll
      for (int j = 0; j < 4; ++j) acc[i][j] = 0.f;
#pragma unroll 2
    for (int k = 0; k < 64; ++k) {
      float4 y4 = *reinterpret_cast<const float4*>(&Y1[(size_t)k * NF_ + n0 + tcA * 4]);
      float a1 = ab[k], c1 = ab[64 + k];
      float bx[4];
      bx[0] = fmaxf(fmaf(y4.x, a1, c1), 0.f);
      bx[1] = fmaxf(fmaf(y4.y, a1, c1), 0.f);
      bx[2] = fmaxf(fmaf(y4.z, a1, c1), 0.f);
      bx[3] = fmaxf(fmaf(y4.w, a1, c1), 0.f);
      const float4* ap = reinterpret_cast<const float4*>(&W2L[k * 128 + tmA * 8]);
      float4 a0 = ap[0], a4 = ap[1];
      const float av[8] = {a0.x, a0.y, a0.z, a0.w, a4.x, a4.y, a4.z, a4.w};
#pragma unroll
      for (int i = 0; i < 8; ++i)
#pragma unroll
        for (int j = 0; j < 4; ++j) acc[i][j] = fmaf(av[i], bx[j], acc[i][j]);
    }
#pragma unroll
    for (int i = 0; i < 8; ++i)
#pragma unroll
      for (int j = 0; j < 4; ++j) {
        if (MODE == 0) {
          float d = acc[i][j] - par0[i];
          vacc[i] = fmaf(d, d, vacc[i]);
        } else {
          vacc[i] += fmaxf(fmaf(acc[i][j], par0[i], par1[i]), 0.f);
        }
      }
  }
#pragma unroll
  for (int i = 0; i < 8; ++i) vpart[tcA][tmA * 8 + i] = vacc[i];
  __syncthreads();
  if (t < 128) {
    float s = 0.f;
    for (int q = 0; q < 16; ++q) s += vpart[q][t];
    parts[(size_t)blockIdx.x * 128 + t] = s;
  }
}

// ============ var3 pass: y3 = W3 * relu(A2*(W2*x1)+D2), accumulate (y3-mu3')^2 ============
__global__ __launch_bounds__(256) void var3_kernel(const float* __restrict__ Y1,
                                                   const float* __restrict__ W2,
                                                   const float* __restrict__ W3,
                                                   const float* __restrict__ A1v,
                                                   const float* __restrict__ Bc1v,
                                                   const float* __restrict__ A2v,
                                                   const float* __restrict__ D2v,
                                                   const double* __restrict__ mu3p,
                                                   float* __restrict__ parts) {
  __shared__ float W2L[64 * 128];     // persistent
  __shared__ float ab[128];
  __shared__ float X2s[128 * 68];
  __shared__ float W3c[16 * 256];
  __shared__ float vpart3[8][256];
  const int t = threadIdx.x;
#pragma unroll
  for (int p = 0; p < 32; ++p) {
    int idx = t + 256 * p;
    int m = idx >> 6, k = idx & 63;
    W2L[k * 128 + m] = W2[m * 64 + k];
  }
  if (t < 64) { ab[t] = A1v[t]; ab[64 + t] = Bc1v[t]; }
  const int tmA = t >> 4, tcA = t & 15;
  const int tm3 = t & 31, tcol = t >> 5;
  float a2r[8], d2r[8], mu3[8], vacc[8];
#pragma unroll
  for (int i = 0; i < 8; ++i) {
    a2r[i] = A2v[tmA * 8 + i];
    d2r[i] = D2v[tmA * 8 + i];
    mu3[i] = (float)mu3p[tm3 * 8 + i];
    vacc[i] = 0.f;
  }
  __syncthreads();
  for (int ch = blockIdx.x; ch < NCH_; ch += 256) {
    const size_t n0 = (size_t)ch * 64;
    {
      float acc[8][4];
#pragma unroll
      for (int i = 0; i < 8; ++i)
#pragma unroll
        for (int j = 0; j < 4; ++j) acc[i][j] = 0.f;
#pragma unroll 2
      for (int k = 0; k < 64; ++k) {
        float4 y4 = *reinterpret_cast<const float4*>(&Y1[(size_t)k * NF_ + n0 + tcA * 4]);
        float a1 = ab[k], c1 = ab[64 + k];
        float bx[4];
        bx[0] = fmaxf(fmaf(y4.x, a1, c1), 0.f);
        bx[1] = fmaxf(fmaf(y4.y, a1, c1), 0.f);
        bx[2] = fmaxf(fmaf(y4.z, a1, c1), 0.f);
        bx[3] = fmaxf(fmaf(y4.w, a1, c1), 0.f);
        const float4* ap = reinterpret_cast<const float4*>(&W2L[k * 128 + tmA * 8]);
        float4 a0 = ap[0], a4 = ap[1];
        const float av[8] = {a0.x, a0.y, a0.z, a0.w, a4.x, a4.y, a4.z, a4.w};
#pragma unroll
        for (int i = 0; i < 8; ++i)
#pragma unroll
          for (int j = 0; j < 4; ++j) acc[i][j] = fmaf(av[i], bx[j], acc[i][j]);
      }
#pragma unroll
      for (int i = 0; i < 8; ++i) {
        float4 v;
        v.x = fmaxf(fmaf(acc[i][0], a2r[i], d2r[i]), 0.f);
        v.y = fmaxf(fmaf(acc[i][1], a2r[i], d2r[i]), 0.f);
        v.z = fmaxf(fmaf(acc[i][2], a2r[i], d2r[i]), 0.f);
        v.w = fmaxf(fmaf(acc[i][3], a2r[i], d2r[i]), 0.f);
        *reinterpret_cast<float4*>(&X2s[(tmA * 8 + i) * 68 + tcA * 4]) = v;
      }
    }
    __syncthreads();
    float acc3[8][8];
#pragma unroll
    for (int i = 0; i < 8; ++i)
#pragma unroll
      for (int j = 0; j < 8; ++j) acc3[i][j] = 0.f;
    for (int kc = 0; kc < 8; ++kc) {
#pragma unroll
      for (int q = 0; q < 4; ++q) {
        float4 w = *reinterpret_cast<const float4*>(&W3[(size_t)t * 128 + kc * 16 + q * 4]);
        W3c[(q * 4 + 0) * 256 + t] = w.x;
        W3c[(q * 4 + 1) * 256 + t] = w.y;
        W3c[(q * 4 + 2) * 256 + t] = w.z;
        W3c[(q * 4 + 3) * 256 + t] = w.w;
      }
      __syncthreads();
#pragma unroll
      for (int kk = 0; kk < 16; ++kk) {
        const float4* ap = reinterpret_cast<const float4*>(&W3c[kk * 256 + tm3 * 8]);
        float4 a0 = ap[0], a4 = ap[1];
        const float4* bp = reinterpret_cast<const float4*>(&X2s[(kc * 16 + kk) * 68 + tcol * 8]);
        float4 b0 = bp[0], b4 = bp[1];
        const float av[8] = {a0.x, a0.y, a0.z, a0.w, a4.x, a4.y, a4.z, a4.w};
        const float bw[8] = {b0.x, b0.y, b0.z, b0.w, b4.x, b4.y, b4.z, b4.w};
#pragma unroll
        for (int i = 0; i < 8; ++i)
#pragma unroll
          for (int j = 0; j < 8; ++j) acc3[i][j] = fmaf(av[i], bw[j], acc3[i][j]);
      }
      __syncthreads();
    }
#pragma unroll
    for (int i = 0; i < 8; ++i)
#pragma unroll
      for (int j = 0; j < 8; ++j) {
        float d = acc3[i][j] - mu3[i];
        vacc[i] = fmaf(d, d, vacc[i]);
      }
    __syncthreads();
  }
#pragma unroll
  for (int i = 0; i < 8; ++i) vpart3[tcol][tm3 * 8 + i] = vacc[i];
  __syncthreads();
  {
    float s = 0.f;
    for (int q = 0; q < 8; ++q) s += vpart3[q][t];
    parts[(size_t)blockIdx.x * 256 + t] = s;
  }
}

// ============ final pass: GEMM2 -> BN -> relu -> GEMM3 -> BN -> max over k -> relu -> out1 ============
__global__ __launch_bounds__(256) void final_kernel(const float* __restrict__ Y1,
                                                    const float* __restrict__ W2,
                                                    const float* __restrict__ W3,
                                                    const float* __restrict__ A1v,
                                                    const float* __restrict__ Bc1v,
                                                    const float* __restrict__ A2v,
                                                    const float* __restrict__ D2v,
                                                    const float* __restrict__ A3v,
                                                    const float* __restrict__ D3v,
                                                    float* __restrict__ out1) {
  __shared__ float W2L[64 * 128];   // aliased as W3c in phase B
  __shared__ float ab[128];
  __shared__ float X2s[128 * 68];
  float* W3c = W2L;
  const int t = threadIdx.x;
#pragma unroll
  for (int p = 0; p < 32; ++p) {
    int idx = t + 256 * p;
    int m = idx >> 6, k = idx & 63;
    W2L[k * 128 + m] = W2[m * 64 + k];
  }
  if (t < 64) { ab[t] = A1v[t]; ab[64 + t] = Bc1v[t]; }
  const int tmA = t >> 4, tcA = t & 15;
  const int tm3 = t & 31, tcol = t >> 5;
  float a2r[8], d2r[8], a3r[8], d3r[8];
#pragma unroll
  for (int i = 0; i < 8; ++i) {
    a2r[i] = A2v[tmA * 8 + i];
    d2r[i] = D2v[tmA * 8 + i];
    a3r[i] = A3v[tm3 * 8 + i];
    d3r[i] = D3v[tm3 * 8 + i];
  }
  __syncthreads();
  const int ch = blockIdx.x;
  const size_t n0 = (size_t)ch * 64;
  {
    float acc[8][4];
#pragma unroll
    for (int i = 0; i < 8; ++i)
#pragma unroll
      for (int j = 0; j < 4; ++j) acc[i][j] = 0.f;
#pragma unroll 2
    for (int k = 0; k < 64; ++k) {
      float4 y4 = *reinterpret_cast<const float4*>(&Y1[(size_t)k * NF_ + n0 + tcA * 4]);
      float a1 = ab[k], c1 = ab[64 + k];
      float bx[4];
      bx[0] = fmaxf(fmaf(y4.x, a1, c1), 0.f);
      bx[1] = fmaxf(fmaf(y4.y, a1, c1), 0.f);
      bx[2] = fmaxf(fmaf(y4.z, a1, c1), 0.f);
      bx[3] = fmaxf(fmaf(y4.w, a1, c1), 0.f);
      const float4* ap = reinterpret_cast<const float4*>(&W2L[k * 128 + tmA * 8]);
      float4 a0 = ap[0], a4 = ap[1];
      const float av[8] = {a0.x, a0.y, a0.z, a0.w, a4.x, a4.y, a4.z, a4.w};
#pragma unroll
      for (int i = 0; i < 8; ++i)
#pragma unroll
        for (int j = 0; j < 4; ++j) acc[i][j] = fmaf(av[i], bx[j], acc[i][j]);
    }
#pragma unroll
    for (int i = 0; i < 8; ++i) {
      float4 v;
      v.x = fmaxf(fmaf(acc[i][0], a2r[i], d2r[i]), 0.f);
      v.y = fmaxf(fmaf(acc[i][1], a2r[i], d2r[i]), 0.f);
      v.z = fmaxf(fmaf(acc[i][2], a2r[i], d2r[i]), 0.f);
      v.w = fmaxf(fmaf(acc[i][3], a2r[i], d2r[i]), 0.f);
      *reinterpret_cast<float4*>(&X2s[(tmA * 8 + i) * 68 + tcA * 4]) = v;
    }
  }
  __syncthreads();
  float acc3[8][8];
#pragma unroll
  for (int i = 0; i < 8; ++i)
#pragma unroll
    for (int j = 0; j < 8; ++j) acc3[i][j] = 0.f;
  for (int kc = 0; kc < 8; ++kc) {
#pragma unroll
    for (int q = 0; q < 4; ++q) {
      float4 w = *reinterpret_cast<const float4*>(&W3[(size_t)t * 128 + kc * 16 + q * 4]);
      W3c[(q * 4 + 0) * 256 + t] = w.x;
      W3c[(q * 4 + 1) * 256 + t] = w.y;
      W3c[(q * 4 + 2) * 256 + t] = w.z;
      W3c[(q * 4 + 3) * 256 + t] = w.w;
    }
    __syncthreads();
#pragma unroll
    for (int kk = 0; kk < 16; ++kk) {
      const float4* ap = reinterpret_cast<const float4*>(&W3c[kk * 256 + tm3 * 8]);
      float4 a0 = ap[0], a4 = ap[1];
      const float4* bp = reinterpret_cast<const float4*>(&X2s[(kc * 16 + kk) * 68 + tcol * 8]);
      float4 b0 = bp[0], b4 = bp[1];
      const float av[8] = {a0.x, a0.y, a0.z, a0.w, a4.x, a4.y, a4.z, a4.w};
      const float bw[8] = {b0.x, b0.y, b0.z, b0.w, b4.x, b4.y, b4.z, b4.w};
#pragma unroll
      for (int i = 0; i < 8; ++i)
#pragma unroll
        for (int j = 0; j < 8; ++j) acc3[i][j] = fmaf(av[i], bw[j], acc3[i][j]);
    }
    __syncthreads();
  }
#pragma unroll
  for (int i = 0; i < 8; ++i) {
    float mx = -__builtin_inff();
#pragma unroll
    for (int j = 0; j < 8; ++j) {
      float v = fmaf(acc3[i][j], a3r[i], d3r[i]);
      mx = fmaxf(mx, v);
    }
    float o = __shfl_xor(mx, 32, 64);
    mx = fmaxf(mx, o);
    if ((tcol & 1) == 0) {
      int g = tcol >> 1;
      int bs = ch * 4 + g;
      int b = bs / S_;
      int s = bs - b * S_;
      out1[((size_t)(b * 256 + tm3 * 8 + i)) * S_ + s] = fmaxf(mx, 0.f);
    }
  }
}

__global__ void diag_kernel(float* out, float v) {
  if (threadIdx.x == 0 && blockIdx.x == 0) out[0] = v;
}

extern "C" void kernel_launch(void* const* d_in, const int* in_sizes, int n_in,
                              void* d_out, int out_size, void* d_ws, size_t ws_size,
                              hipStream_t stream) {
  const float* xy  = (const float*)d_in[0];
  const float* fea = (const float*)d_in[1];
  const float* W1  = (const float*)d_in[2];
  const float* b1  = (const float*)d_in[3];
  const float* g1  = (const float*)d_in[4];
  const float* be1 = (const float*)d_in[5];
  const float* W2  = (const float*)d_in[6];
  const float* b2  = (const float*)d_in[7];
  const float* g2  = (const float*)d_in[8];
  const float* be2 = (const float*)d_in[9];
  const float* W3  = (const float*)d_in[10];
  const float* b3  = (const float*)d_in[11];
  const float* g3  = (const float*)d_in[12];
  const float* be3 = (const float*)d_in[13];
  (void)b2; (void)b3;
  float* out = (float*)d_out;
  float* out1 = out + B_ * 2 * S_;

  char* w = (char*)d_ws;
  size_t off = 0;
  auto take = [&](size_t bytes) -> void* {
    void* p = w + off;
    off += (bytes + 255) & ~(size_t)255;
    return p;
  };
  int*    fps_idx = (int*)take((size_t)B_ * S_ * 4);
  float*  new_xyz = (float*)take((size_t)B_ * S_ * 2 * 4);
  int*    knn_sel = (int*)take((size_t)NF_ * 4);
  float*  P       = (float*)take((size_t)B_ * N_ * 64 * 4);   // 8.4 MB
  float*  Y1      = (float*)take((size_t)64 * NF_ * 4);       // 67.2 MB
  double* Sy1     = (double*)take(64 * 8);
  double* var1r   = (double*)take(64 * 8);
  float*  A1      = (float*)take(64 * 4);
  float*  Bc1     = (float*)take(64 * 4);
  double* S1      = (double*)take(64 * 8);
  double* mu2p    = (double*)take(128 * 8);
  float*  var2p   = (float*)take((size_t)512 * 128 * 4);
  double* var2r   = (double*)take(128 * 8);
  float*  A2      = (float*)take(128 * 4);
  float*  D2      = (float*)take(128 * 4);
  float*  s2p     = (float*)take((size_t)512 * 128 * 4);
  double* S2      = (double*)take(128 * 8);
  double* mu3p    = (double*)take(256 * 8);
  float*  var3p   = (float*)take((size_t)256 * 256 * 4);
  double* var3r   = (double*)take(256 * 8);
  float*  A3      = (float*)take(256 * 4);
  float*  D3      = (float*)take(256 * 4);

  if (off > ws_size) {
    diag_kernel<<<1, 64, 0, stream>>>(out, (float)(ws_size >> 20));
    return;
  }

  fps_kernel<<<B_, 64, 0, stream>>>(xy, fps_idx, new_xyz, out);
  knn_kernel<<<dim3((S_ + 31) / 32, B_), 256, 0, stream>>>(xy, fps_idx, knn_sel);
  pk_kernel<<<B_ * 32, 256, 0, stream>>>(fea, W1, P);
  yk1_kernel<<<NF_ / 256, 256, 0, stream>>>(xy, knn_sel, new_xyz, P, W1, b1, Y1);

  rowsum_kernel<false><<<64, 1024, 0, stream>>>(Y1, nullptr, nullptr, Sy1);
  rowvar_kernel<<<64, 1024, 0, stream>>>(Y1, Sy1, var1r);
  absch_kernel<<<1, 64, 0, stream>>>(Sy1, var1r, g1, be1, A1, Bc1, 64, 1);
  rowsum_kernel<true><<<64, 1024, 0, stream>>>(Y1, A1, Bc1, S1);

  meanlin_kernel<<<1, 128, 0, stream>>>(W2, S1, mu2p, 128, 64);
  pass2_kernel<0><<<512, 256, 0, stream>>>(Y1, W2, A1, Bc1, mu2p, nullptr, nullptr, var2p);
  red_kernel<<<1, 128, 0, stream>>>(var2p, var2r, 512, 128);
  absch_kernel<<<1, 128, 0, stream>>>(mu2p, var2r, g2, be2, A2, D2, 128, 0);

  pass2_kernel<1><<<512, 256, 0, stream>>>(Y1, W2, A1, Bc1, nullptr, A2, D2, s2p);
  red_kernel<<<1, 128, 0, stream>>>(s2p, S2, 512, 128);
  meanlin_kernel<<<1, 256, 0, stream>>>(W3, S2, mu3p, 256, 128);

  var3_kernel<<<256, 256, 0, stream>>>(Y1, W2, W3, A1, Bc1, A2, D2, mu3p, var3p);
  red_kernel<<<1, 256, 0, stream>>>(var3p, var3r, 256, 256);
  absch_kernel<<<1, 256, 0, stream>>>(mu3p, var3r, g3, be3, A3, D3, 256, 0);

  final_kernel<<<NCH_, 256, 0, stream>>>(Y1, W2, W3, A1, Bc1, A2, D2, A3, D3, out1);
}

// Round 5
// 3185.272 us; speedup vs baseline: 1.4483x; 1.0516x over previous
//
#include <hip/hip_runtime.h>
#include <math.h>

#define B_   16
#define N_   2048
#define S_   1025
#define K_   16
#define EMB_ 64
#define NF_  (B_ * S_ * K_)   // 262400
#define NCH_ (NF_ / 64)       // 4100 column-chunks of 64

// ---------------- FPS: ONE WAVE per batch, fp32 BIT-EXACT replication of reference ----------
// d = rn(rn(dx*dx) + rn(dy*dy)), dx = rn(px - cx)  -- no FMA contraction (__f*_rn intrinsics),
// running fminf == jnp.minimum, argmax with lowest-index tie-break == jnp.argmax.
// Lane l owns contiguous points [l*32, l*32+32) so (first lane hit, first local j) == global argmax.
__global__ __launch_bounds__(64) void fps_kernel(const float* __restrict__ xy,
                                                 int* __restrict__ fps_idx,
                                                 float* __restrict__ new_xyz,
                                                 float* __restrict__ out0) {
  const int b = blockIdx.x;
  const int lane = threadIdx.x;   // 0..63
  __shared__ float2 lxy[N_];      // 16 KB
  const float* xb = xy + (size_t)b * 2 * N_;
  float px[32], py[32], dist[32];
#pragma unroll
  for (int j = 0; j < 32; ++j) {
    int p = lane * 32 + j;
    float x = xb[p], y = xb[N_ + p];
    lxy[p] = make_float2(x, y);
    px[j] = x; py[j] = y;
    dist[j] = __builtin_inff();
  }
  __syncthreads();   // single wave; orders LDS init vs reads
  int cur = 0;
  for (int t = 0; t < S_; ++t) {
    float2 c = lxy[cur];          // broadcast read (same address, no conflict)
    if (lane == 0) {
      fps_idx[b * S_ + t] = cur;
      new_xyz[(b * S_ + t) * 2 + 0] = c.x;
      new_xyz[(b * S_ + t) * 2 + 1] = c.y;
      out0[b * 2 * S_ + t] = c.x;
      out0[b * 2 * S_ + S_ + t] = c.y;
    }
    const float cx = c.x, cy = c.y;
    float lmax = -__builtin_inff();
#pragma unroll
    for (int j = 0; j < 32; ++j) {
      float dx = __fsub_rn(px[j], cx);
      float dy = __fsub_rn(py[j], cy);
      float d = __fadd_rn(__fmul_rn(dx, dx), __fmul_rn(dy, dy));  // exact ref rounding
      float nd = fminf(dist[j], d);
      dist[j] = nd;
      lmax = fmaxf(lmax, nd);
    }
    // exact value-max across the wave (fp32 single-word shuffles)
    float g = lmax;
#pragma unroll
    for (int m = 1; m < 64; m <<= 1) g = fmaxf(g, __shfl_xor(g, m, 64));
    // first local index equal to g (descending scan keeps lowest j)
    int lf = 64;
#pragma unroll
    for (int j = 31; j >= 0; --j)
      if (dist[j] == g) lf = j;
    int gidx = (lf < 32) ? (lane * 32 + lf) : 0x7fffffff;
    unsigned long long mask = __ballot(lf < 32);
    int first = __ffsll(mask) - 1;           // lowest lane with a hit
    cur = __shfl(gidx, first, 64);
  }
}

// ---------------- KNN fp64-exact, 8 lanes per query point, register bitonic merges ----------------
// Lex order (d, idx) == stable top_k tie semantics. Downstream is k-max-pool -> only the SET matters.
__global__ __launch_bounds__(256) void knn_kernel(const float* __restrict__ xy,
                                                  const int* __restrict__ fps_idx,
                                                  int* __restrict__ knn_sel) {
  const int b = blockIdx.y;
  __shared__ float2 lxy[N_];    // 16 KB
  __shared__ double lsq[N_];    // 16 KB
  const float* xb = xy + (size_t)b * 2 * N_;
  for (int p = threadIdx.x; p < N_; p += 256) {
    float x = xb[p], y = xb[N_ + p];
    lxy[p] = make_float2(x, y);
    lsq[p] = (double)x * (double)x + (double)y * (double)y;  // exact
  }
  __syncthreads();
  const int t = threadIdx.x;
  const int s = blockIdx.x * 32 + (t >> 3);
  if (s >= S_) return;          // whole 8-lane group shares s -> uniform exit
  const int oct = t & 7;
  const int p0 = fps_idx[b * S_ + s];
  float2 q = lxy[p0];
  const double xn = (double)q.x, yn = (double)q.y;
  const double sqn = lsq[p0];
  double d16[16];
  int i16[16];
#pragma unroll
  for (int j = 0; j < 16; ++j) { d16[j] = __builtin_inf(); i16[j] = 0x7fffffff; }
  const int mlo = oct * 256;
  for (int m0 = mlo; m0 < mlo + 256; m0 += 4) {
    double dd[4];
#pragma unroll
    for (int u = 0; u < 4; ++u) {
      float2 p = lxy[m0 + u];
      double dot = (double)p.x * xn + (double)p.y * yn;   // exact products -> fma == mul,mul,add
      dd[u] = (sqn - 2.0 * dot) + lsq[m0 + u];            // reference rounding order
    }
#pragma unroll
    for (int u = 0; u < 4; ++u) {
      if (dd[u] < d16[15]) {   // strict <: within ascending scan this is lex-correct
        double d = dd[u];
        int mi = m0 + u;
#pragma unroll
        for (int j = 15; j >= 1; --j) {
          bool shift = d < d16[j - 1];
          bool ins = d < d16[j];
          d16[j] = shift ? d16[j - 1] : (ins ? d : d16[j]);
          i16[j] = shift ? i16[j - 1] : (ins ? mi : i16[j]);
        }
        if (d < d16[0]) { d16[0] = d; i16[0] = mi; }
      }
    }
  }
  // 3 merge rounds across the 8-lane group (xor 1,2,4).
#pragma unroll
  for (int w = 1; w <= 4; w <<= 1) {
    double nd[16]; int ni[16];
#pragma unroll
    for (int i = 0; i < 16; ++i) {
      double rd = __shfl_xor(d16[15 - i], w, 64);
      int ri = __shfl_xor(i16[15 - i], w, 64);
      bool takeR = (rd < d16[i]) || (rd == d16[i] && ri < i16[i]);
      nd[i] = takeR ? rd : d16[i];
      ni[i] = takeR ? ri : i16[i];
    }
#pragma unroll
    for (int i = 0; i < 16; ++i) { d16[i] = nd[i]; i16[i] = ni[i]; }
    if (w < 4) {
#pragma unroll
      for (int dstg = 8; dstg >= 1; dstg >>= 1) {
#pragma unroll
        for (int i = 0; i < 16; ++i) {
          if ((i & dstg) == 0) {
            int a = i, c = i + dstg;
            bool sw = (d16[a] > d16[c]) || (d16[a] == d16[c] && i16[a] > i16[c]);
            double tlo = sw ? d16[c] : d16[a];
            double thi = sw ? d16[a] : d16[c];
            int ulo = sw ? i16[c] : i16[a];
            int uhi = sw ? i16[a] : i16[c];
            d16[a] = tlo; d16[c] = thi; i16[a] = ulo; i16[c] = uhi;
          }
        }
      }
    }
  }
  if (oct == 0) {
    int* dst = knn_sel + ((size_t)b * S_ + s) * K_;
#pragma unroll
    for (int j = 0; j < 16; ++j) dst[j] = i16[j];
  }
}

// ---------------- P[b][pt][c] = sum_e W1[c][2+e] * fea[b][e][pt] ----------------
__global__ __launch_bounds__(256) void pk_kernel(const float* __restrict__ fea,
                                                 const float* __restrict__ W1,
                                                 float* __restrict__ P) {
  const int t = threadIdx.x;
  const int b = blockIdx.x >> 5;
  const int pt0 = (blockIdx.x & 31) << 6;
  __shared__ float W1L[64 * 64];   // [e][c]
  __shared__ float feaL[64 * 64];  // [e][pt]
#pragma unroll
  for (int p = 0; p < 16; ++p) {
    int idx = t + 256 * p;
    int c = idx >> 6, e = idx & 63;
    W1L[e * 64 + c] = W1[c * 66 + 2 + e];
    int r = (t >> 6) + 4 * p, cc = t & 63;
    feaL[r * 64 + cc] = fea[((size_t)b * 64 + r) * N_ + pt0 + cc];
  }
  __syncthreads();
  const int tpt = t & 15, tcq = t >> 4;
  float acc[4][4];
#pragma unroll
  for (int i = 0; i < 4; ++i)
#pragma unroll
    for (int j = 0; j < 4; ++j) acc[i][j] = 0.f;
  for (int e = 0; e < 64; ++e) {
    float4 a4 = *reinterpret_cast<const float4*>(&W1L[e * 64 + tcq * 4]);
    float4 b4 = *reinterpret_cast<const float4*>(&feaL[e * 64 + tpt * 4]);
    const float av[4] = {a4.x, a4.y, a4.z, a4.w};
    const float bvv[4] = {b4.x, b4.y, b4.z, b4.w};
#pragma unroll
    for (int i = 0; i < 4; ++i)
#pragma unroll
      for (int j = 0; j < 4; ++j) acc[i][j] = fmaf(av[i], bvv[j], acc[i][j]);
  }
#pragma unroll
  for (int j = 0; j < 4; ++j) {
    int pt = tpt * 4 + j;
    float4 v = {acc[0][j], acc[1][j], acc[2][j], acc[3][j]};
    *reinterpret_cast<float4*>(&P[((size_t)(b * N_ + pt0 + pt)) * 64 + tcq * 4]) = v;
  }
}

// ---------------- Y1[64][NF]: gather P + W1a*dxy + b1 ----------------
__global__ __launch_bounds__(256) void yk1_kernel(const float* __restrict__ xy,
                                                  const int* __restrict__ knn_sel,
                                                  const float* __restrict__ new_xyz,
                                                  const float* __restrict__ P,
                                                  const float* __restrict__ W1,
                                                  const float* __restrict__ b1,
                                                  float* __restrict__ Y1) {
  __shared__ float w0s[64], w1s[64], bbs[64];
  const int t = threadIdx.x;
  if (t < 64) { w0s[t] = W1[t * 66 + 0]; w1s[t] = W1[t * 66 + 1]; bbs[t] = b1[t]; }
  __syncthreads();
  const int n = blockIdx.x * 256 + t;
  const int bs = n >> 4;
  const int b = bs / S_;
  const int nbr = knn_sel[n];
  const float dx = xy[(size_t)b * 2 * N_ + nbr] - new_xyz[bs * 2 + 0];
  const float dy = xy[(size_t)b * 2 * N_ + N_ + nbr] - new_xyz[bs * 2 + 1];
  const float* prow = &P[((size_t)(b * N_ + nbr)) * 64];
  for (int c4 = 0; c4 < 64; c4 += 4) {
    float4 p4 = *reinterpret_cast<const float4*>(&prow[c4]);
    float v0 = p4.x + w0s[c4 + 0] * dx + w1s[c4 + 0] * dy + bbs[c4 + 0];
    float v1 = p4.y + w0s[c4 + 1] * dx + w1s[c4 + 1] * dy + bbs[c4 + 1];
    float v2 = p4.z + w0s[c4 + 2] * dx + w1s[c4 + 2] * dy + bbs[c4 + 2];
    float v3 = p4.w + w0s[c4 + 3] * dx + w1s[c4 + 3] * dy + bbs[c4 + 3];
    Y1[(size_t)(c4 + 0) * NF_ + n] = v0;
    Y1[(size_t)(c4 + 1) * NF_ + n] = v1;
    Y1[(size_t)(c4 + 2) * NF_ + n] = v2;
    Y1[(size_t)(c4 + 3) * NF_ + n] = v3;
  }
}

// ---------------- per-row sum (optionally affine+relu), double accumulators ----------------
template <bool AFF>
__global__ __launch_bounds__(1024) void rowsum_kernel(const float* __restrict__ Y,
                                                      const float* __restrict__ A,
                                                      const float* __restrict__ Bc,
                                                      double* __restrict__ out) {
  const int r = blockIdx.x;
  const float a = AFF ? A[r] : 0.f, c = AFF ? Bc[r] : 0.f;
  double s = 0.0;
  for (int i = threadIdx.x; i < NF_; i += 1024) {
    float v = Y[(size_t)r * NF_ + i];
    if (AFF) v = fmaxf(fmaf(v, a, c), 0.f);
    s += (double)v;
  }
  __shared__ double sh[1024];
  sh[threadIdx.x] = s;
  __syncthreads();
  for (int o = 512; o > 0; o >>= 1) {
    if (threadIdx.x < o) sh[threadIdx.x] += sh[threadIdx.x + o];
    __syncthreads();
  }
  if (threadIdx.x == 0) out[r] = sh[0];
}

// ---------------- per-row centered sumsq ----------------
__global__ __launch_bounds__(1024) void rowvar_kernel(const float* __restrict__ Y,
                                                      const double* __restrict__ sums,
                                                      double* __restrict__ out) {
  const int r = blockIdx.x;
  const double mu = sums[r] * (1.0 / NF_);
  double s = 0.0;
  for (int i = threadIdx.x; i < NF_; i += 1024) {
    double d = (double)Y[(size_t)r * NF_ + i] - mu;
    s += d * d;
  }
  __shared__ double sh[1024];
  sh[threadIdx.x] = s;
  __syncthreads();
  for (int o = 512; o > 0; o >>= 1) {
    if (threadIdx.x < o) sh[threadIdx.x] += sh[threadIdx.x + o];
    __syncthreads();
  }
  if (threadIdx.x == 0) out[r] = sh[0];
}

// ---------------- A = g*rsqrt(var+eps); D = be - A*mu ----------------
__global__ void absch_kernel(const double* __restrict__ muv, const double* __restrict__ varraw,
                             const float* __restrict__ g, const float* __restrict__ be,
                             float* __restrict__ A, float* __restrict__ D, int M, int mu_is_sum) {
  int m = threadIdx.x;
  if (m >= M) return;
  double mu = mu_is_sum ? muv[m] * (1.0 / NF_) : muv[m];
  double var = varraw[m] * (1.0 / NF_);
  double a = (double)g[m] / sqrt(var + 1e-5);
  A[m] = (float)a;
  D[m] = (float)((double)be[m] - a * mu);
}

// ---------------- mu[m] = dot(W[m,:K], S)/NF ----------------
__global__ void meanlin_kernel(const float* __restrict__ W, const double* __restrict__ S,
                               double* __restrict__ mu, int M, int K) {
  int m = threadIdx.x;
  if (m >= M) return;
  double acc = 0.0;
  for (int k = 0; k < K; ++k) acc += (double)W[m * K + k] * S[k];
  mu[m] = acc * (1.0 / NF_);
}

// ---------------- reduce partials [P][M] -> double[M] ----------------
__global__ void red_kernel(const float* __restrict__ parts, double* __restrict__ out, int P, int M) {
  int m = threadIdx.x;
  if (m >= M) return;
  double a = 0.0;
  for (int p = 0; p < P; ++p) a += (double)parts[(size_t)p * M + m];
  out[m] = a;
}

// ============ GEMM2 pass kernels: y2[128][64cols] per chunk, x1 from Y1 on the fly ============
template <int MODE>  // 0: accumulate (y2-mu2')^2 ; 1: accumulate relu(A2*y2+D2)
__global__ __launch_bounds__(256) void pass2_kernel(const float* __restrict__ Y1,
                                                    const float* __restrict__ W2,
                                                    const float* __restrict__ A1v,
                                                    const float* __restrict__ Bc1v,
                                                    const double* __restrict__ mu2p,
                                                    const float* __restrict__ A2v,
                                                    const float* __restrict__ D2v,
                                                    float* __restrict__ parts) {
  __shared__ float W2L[64 * 128];
  __shared__ float ab[128];
  __shared__ float vpart[16][128];
  const int t = threadIdx.x;
#pragma unroll
  for (int p = 0; p < 32; ++p) {
    int idx = t + 256 * p;
    int m = idx >> 6, k = idx & 63;
    W2L[k * 128 + m] = W2[m * 64 + k];
  }
  if (t < 64) { ab[t] = A1v[t]; ab[64 + t] = Bc1v[t]; }
  const int tmA = t >> 4, tcA = t & 15;
  float par0[8], par1[8], vacc[8];
#pragma unroll
  for (int i = 0; i < 8; ++i) {
    int m = tmA * 8 + i;
    if (MODE == 0) { par0[i] = (float)mu2p[m]; par1[i] = 0.f; }
    else { par0[i] = A2v[m]; par1[i] = D2v[m]; }
    vacc[i] = 0.f;
  }
  __syncthreads();
  for (int ch = blockIdx.x; ch < NCH_; ch += 512) {
    const size_t n0 = (size_t)ch * 64;
    float acc[8][4];
#pragma unroll
    for (int i = 0; i < 8; ++i)
#pragma unroll
      for (int j = 0; j < 4; ++j) acc[i][j] = 0.f;
#pragma unroll 2
    for (int k = 0; k < 64; ++k) {
      float4 y4 = *reinterpret_cast<const float4*>(&Y1[(size_t)k * NF_ + n0 + tcA * 4]);
      float a1 = ab[k], c1 = ab[64 + k];
      float bx[4];
      bx[0] = fmaxf(fmaf(y4.x, a1, c1), 0.f);
      bx[1] = fmaxf(fmaf(y4.y, a1, c1), 0.f);
      bx[2] = fmaxf(fmaf(y4.z, a1, c1), 0.f);
      bx[3] = fmaxf(fmaf(y4.w, a1, c1), 0.f);
      const float4* ap = reinterpret_cast<const float4*>(&W2L[k * 128 + tmA * 8]);
      float4 a0 = ap[0], a4 = ap[1];
      const float av[8] = {a0.x, a0.y, a0.z, a0.w, a4.x, a4.y, a4.z, a4.w};
#pragma unroll
      for (int i = 0; i < 8; ++i)
#pragma unroll
        for (int j = 0; j < 4; ++j) acc[i][j] = fmaf(av[i], bx[j], acc[i][j]);
    }
#pragma unroll
    for (int i = 0; i < 8; ++i)
#pragma unroll
      for (int j = 0; j < 4; ++j) {
        if (MODE == 0) {
          float d = acc[i][j] - par0[i];
          vacc[i] = fmaf(d, d, vacc[i]);
        } else {
          vacc[i] += fmaxf(fmaf(acc[i][j], par0[i], par1[i]), 0.f);
        }
      }
  }
#pragma unroll
  for (int i = 0; i < 8; ++i) vpart[tcA][tmA * 8 + i] = vacc[i];
  __syncthreads();
  if (t < 128) {
    float s = 0.f;
    for (int q = 0; q < 16; ++q) s += vpart[q][t];
    parts[(size_t)blockIdx.x * 128 + t] = s;
  }
}

// ============ var3 pass: y3 = W3 * relu(A2*(W2*x1)+D2), accumulate (y3-mu3')^2 ============
__global__ __launch_bounds__(256) void var3_kernel(const float* __restrict__ Y1,
                                                   const float* __restrict__ W2,
                                                   const float* __restrict__ W3,
                                                   const float* __restrict__ A1v,
                                                   const float* __restrict__ Bc1v,
                                                   const float* __restrict__ A2v,
                                                   const float* __restrict__ D2v,
                                                   const double* __restrict__ mu3p,
                                                   float* __restrict__ parts) {
  __shared__ float W2L[64 * 128];     // persistent
  __shared__ float ab[128];
  __shared__ float X2s[128 * 68];
  __shared__ float W3c[16 * 256];
  __shared__ float vpart3[8][256];
  const int t = threadIdx.x;
#pragma unroll
  for (int p = 0; p < 32; ++p) {
    int idx = t + 256 * p;
    int m = idx >> 6, k = idx & 63;
    W2L[k * 128 + m] = W2[m * 64 + k];
  }
  if (t < 64) { ab[t] = A1v[t]; ab[64 + t] = Bc1v[t]; }
  const int tmA = t >> 4, tcA = t & 15;
  const int tm3 = t & 31, tcol = t >> 5;
  float a2r[8], d2r[8], mu3[8], vacc[8];
#pragma unroll
  for (int i = 0; i < 8; ++i) {
    a2r[i] = A2v[tmA * 8 + i];
    d2r[i] = D2v[tmA * 8 + i];
    mu3[i] = (float)mu3p[tm3 * 8 + i];
    vacc[i] = 0.f;
  }
  __syncthreads();
  for (int ch = blockIdx.x; ch < NCH_; ch += 256) {
    const size_t n0 = (size_t)ch * 64;
    {
      float acc[8][4];
#pragma unroll
      for (int i = 0; i < 8; ++i)
#pragma unroll
        for (int j = 0; j < 4; ++j) acc[i][j] = 0.f;
#pragma unroll 2
      for (int k = 0; k < 64; ++k) {
        float4 y4 = *reinterpret_cast<const float4*>(&Y1[(size_t)k * NF_ + n0 + tcA * 4]);
        float a1 = ab[k], c1 = ab[64 + k];
        float bx[4];
        bx[0] = fmaxf(fmaf(y4.x, a1, c1), 0.f);
        bx[1] = fmaxf(fmaf(y4.y, a1, c1), 0.f);
        bx[2] = fmaxf(fmaf(y4.z, a1, c1), 0.f);
        bx[3] = fmaxf(fmaf(y4.w, a1, c1), 0.f);
        const float4* ap = reinterpret_cast<const float4*>(&W2L[k * 128 + tmA * 8]);
        float4 a0 = ap[0], a4 = ap[1];
        const float av[8] = {a0.x, a0.y, a0.z, a0.w, a4.x, a4.y, a4.z, a4.w};
#pragma unroll
        for (int i = 0; i < 8; ++i)
#pragma unroll
          for (int j = 0; j < 4; ++j) acc[i][j] = fmaf(av[i], bx[j], acc[i][j]);
      }
#pragma unroll
      for (int i = 0; i < 8; ++i) {
        float4 v;
        v.x = fmaxf(fmaf(acc[i][0], a2r[i], d2r[i]), 0.f);
        v.y = fmaxf(fmaf(acc[i][1], a2r[i], d2r[i]), 0.f);
        v.z = fmaxf(fmaf(acc[i][2], a2r[i], d2r[i]), 0.f);
        v.w = fmaxf(fmaf(acc[i][3], a2r[i], d2r[i]), 0.f);
        *reinterpret_cast<float4*>(&X2s[(tmA * 8 + i) * 68 + tcA * 4]) = v;
      }
    }
    __syncthreads();
    float acc3[8][8];
#pragma unroll
    for (int i = 0; i < 8; ++i)
#pragma unroll
      for (int j = 0; j < 8; ++j) acc3[i][j] = 0.f;
    for (int kc = 0; kc < 8; ++kc) {
#pragma unroll
      for (int q = 0; q < 4; ++q) {
        float4 w = *reinterpret_cast<const float4*>(&W3[(size_t)t * 128 + kc * 16 + q * 4]);
        W3c[(q * 4 + 0) * 256 + t] = w.x;
        W3c[(q * 4 + 1) * 256 + t] = w.y;
        W3c[(q * 4 + 2) * 256 + t] = w.z;
        W3c[(q * 4 + 3) * 256 + t] = w.w;
      }
      __syncthreads();
#pragma unroll
      for (int kk = 0; kk < 16; ++kk) {
        const float4* ap = reinterpret_cast<const float4*>(&W3c[kk * 256 + tm3 * 8]);
        float4 a0 = ap[0], a4 = ap[1];
        const float4* bp = reinterpret_cast<const float4*>(&X2s[(kc * 16 + kk) * 68 + tcol * 8]);
        float4 b0 = bp[0], b4 = bp[1];
        const float av[8] = {a0.x, a0.y, a0.z, a0.w, a4.x, a4.y, a4.z, a4.w};
        const float bw[8] = {b0.x, b0.y, b0.z, b0.w, b4.x, b4.y, b4.z, b4.w};
#pragma unroll
        for (int i = 0; i < 8; ++i)
#pragma unroll
          for (int j = 0; j < 8; ++j) acc3[i][j] = fmaf(av[i], bw[j], acc3[i][j]);
      }
      __syncthreads();
    }
#pragma unroll
    for (int i = 0; i < 8; ++i)
#pragma unroll
      for (int j = 0; j < 8; ++j) {
        float d = acc3[i][j] - mu3[i];
        vacc[i] = fmaf(d, d, vacc[i]);
      }
    __syncthreads();
  }
#pragma unroll
  for (int i = 0; i < 8; ++i) vpart3[tcol][tm3 * 8 + i] = vacc[i];
  __syncthreads();
  {
    float s = 0.f;
    for (int q = 0; q < 8; ++q) s += vpart3[q][t];
    parts[(size_t)blockIdx.x * 256 + t] = s;
  }
}

// ============ final pass: GEMM2 -> BN -> relu -> GEMM3 -> BN -> max over k -> relu -> out1 ============
__global__ __launch_bounds__(256) void final_kernel(const float* __restrict__ Y1,
                                                    const float* __restrict__ W2,
                                                    const float* __restrict__ W3,
                                                    const float* __restrict__ A1v,
                                                    const float* __restrict__ Bc1v,
                                                    const float* __restrict__ A2v,
                                                    const float* __restrict__ D2v,
                                                    const float* __restrict__ A3v,
                                                    const float* __restrict__ D3v,
                                                    float* __restrict__ out1) {
  __shared__ float W2L[64 * 128];   // aliased as W3c in phase B
  __shared__ float ab[128];
  __shared__ float X2s[128 * 68];
  float* W3c = W2L;
  const int t = threadIdx.x;
#pragma unroll
  for (int p = 0; p < 32; ++p) {
    int idx = t + 256 * p;
    int m = idx >> 6, k = idx & 63;
    W2L[k * 128 + m] = W2[m * 64 + k];
  }
  if (t < 64) { ab[t] = A1v[t]; ab[64 + t] = Bc1v[t]; }
  const int tmA = t >> 4, tcA = t & 15;
  const int tm3 = t & 31, tcol = t >> 5;
  float a2r[8], d2r[8], a3r[8], d3r[8];
#pragma unroll
  for (int i = 0; i < 8; ++i) {
    a2r[i] = A2v[tmA * 8 + i];
    d2r[i] = D2v[tmA * 8 + i];
    a3r[i] = A3v[tm3 * 8 + i];
    d3r[i] = D3v[tm3 * 8 + i];
  }
  __syncthreads();
  const int ch = blockIdx.x;
  const size_t n0 = (size_t)ch * 64;
  {
    float acc[8][4];
#pragma unroll
    for (int i = 0; i < 8; ++i)
#pragma unroll
      for (int j = 0; j < 4; ++j) acc[i][j] = 0.f;
#pragma unroll 2
    for (int k = 0; k < 64; ++k) {
      float4 y4 = *reinterpret_cast<const float4*>(&Y1[(size_t)k * NF_ + n0 + tcA * 4]);
      float a1 = ab[k], c1 = ab[64 + k];
      float bx[4];
      bx[0] = fmaxf(fmaf(y4.x, a1, c1), 0.f);
      bx[1] = fmaxf(fmaf(y4.y, a1, c1), 0.f);
      bx[2] = fmaxf(fmaf(y4.z, a1, c1), 0.f);
      bx[3] = fmaxf(fmaf(y4.w, a1, c1), 0.f);
      const float4* ap = reinterpret_cast<const float4*>(&W2L[k * 128 + tmA * 8]);
      float4 a0 = ap[0], a4 = ap[1];
      const float av[8] = {a0.x, a0.y, a0.z, a0.w, a4.x, a4.y, a4.z, a4.w};
#pragma unroll
      for (int i = 0; i < 8; ++i)
#pragma unroll
        for (int j = 0; j < 4; ++j) acc[i][j] = fmaf(av[i], bx[j], acc[i][j]);
    }
#pragma unroll
    for (int i = 0; i < 8; ++i) {
      float4 v;
      v.x = fmaxf(fmaf(acc[i][0], a2r[i], d2r[i]), 0.f);
      v.y = fmaxf(fmaf(acc[i][1], a2r[i], d2r[i]), 0.f);
      v.z = fmaxf(fmaf(acc[i][2], a2r[i], d2r[i]), 0.f);
      v.w = fmaxf(fmaf(acc[i][3], a2r[i], d2r[i]), 0.f);
      *reinterpret_cast<float4*>(&X2s[(tmA * 8 + i) * 68 + tcA * 4]) = v;
    }
  }
  __syncthreads();
  float acc3[8][8];
#pragma unroll
  for (int i = 0; i < 8; ++i)
#pragma unroll
    for (int j = 0; j < 8; ++j) acc3[i][j] = 0.f;
  for (int kc = 0; kc < 8; ++kc) {
#pragma unroll
    for (int q = 0; q < 4; ++q) {
      float4 w = *reinterpret_cast<const float4*>(&W3[(size_t)t * 128 + kc * 16 + q * 4]);
      W3c[(q * 4 + 0) * 256 + t] = w.x;
      W3c[(q * 4 + 1) * 256 + t] = w.y;
      W3c[(q * 4 + 2) * 256 + t] = w.z;
      W3c[(q * 4 + 3) * 256 + t] = w.w;
    }
    __syncthreads();
#pragma unroll
    for (int kk = 0; kk < 16; ++kk) {
      const float4* ap = reinterpret_cast<const float4*>(&W3c[kk * 256 + tm3 * 8]);
      float4 a0 = ap[0], a4 = ap[1];
      const float4* bp = reinterpret_cast<const float4*>(&X2s[(kc * 16 + kk) * 68 + tcol * 8]);
      float4 b0 = bp[0], b4 = bp[1];
      const float av[8] = {a0.x, a0.y, a0.z, a0.w, a4.x, a4.y, a4.z, a4.w};
      const float bw[8] = {b0.x, b0.y, b0.z, b0.w, b4.x, b4.y, b4.z, b4.w};
#pragma unroll
      for (int i = 0; i < 8; ++i)
#pragma unroll
        for (int j = 0; j < 8; ++j) acc3[i][j] = fmaf(av[i], bw[j], acc3[i][j]);
    }
    __syncthreads();
  }
#pragma unroll
  for (int i = 0; i < 8; ++i) {
    float mx = -__builtin_inff();
#pragma unroll
    for (int j = 0; j < 8; ++j) {
      float v = fmaf(acc3[i][j], a3r[i], d3r[i]);
      mx = fmaxf(mx, v);
    }
    float o = __shfl_xor(mx, 32, 64);
    mx = fmaxf(mx, o);
    if ((tcol & 1) == 0) {
      int g = tcol >> 1;
      int bs = ch * 4 + g;
      int b = bs / S_;
      int s = bs - b * S_;
      out1[((size_t)(b * 256 + tm3 * 8 + i)) * S_ + s] = fmaxf(mx, 0.f);
    }
  }
}

__global__ void diag_kernel(float* out, float v) {
  if (threadIdx.x == 0 && blockIdx.x == 0) out[0] = v;
}

extern "C" void kernel_launch(void* const* d_in, const int* in_sizes, int n_in,
                              void* d_out, int out_size, void* d_ws, size_t ws_size,
                              hipStream_t stream) {
  const float* xy  = (const float*)d_in[0];
  const float* fea = (const float*)d_in[1];
  const float* W1  = (const float*)d_in[2];
  const float* b1  = (const float*)d_in[3];
  const float* g1  = (const float*)d_in[4];
  const float* be1 = (const float*)d_in[5];
  const float* W2  = (const float*)d_in[6];
  const float* b2  = (const float*)d_in[7];
  const float* g2  = (const float*)d_in[8];
  const float* be2 = (const float*)d_in[9];
  const float* W3  = (const float*)d_in[10];
  const float* b3  = (const float*)d_in[11];
  const float* g3  = (const float*)d_in[12];
  const float* be3 = (const float*)d_in[13];
  (void)b2; (void)b3;
  float* out = (float*)d_out;
  float* out1 = out + B_ * 2 * S_;

  char* w = (char*)d_ws;
  size_t off = 0;
  auto take = [&](size_t bytes) -> void* {
    void* p = w + off;
    off += (bytes + 255) & ~(size_t)255;
    return p;
  };
  int*    fps_idx = (int*)take((size_t)B_ * S_ * 4);
  float*  new_xyz = (float*)take((size_t)B_ * S_ * 2 * 4);
  int*    knn_sel = (int*)take((size_t)NF_ * 4);
  float*  P       = (float*)take((size_t)B_ * N_ * 64 * 4);   // 8.4 MB
  float*  Y1      = (float*)take((size_t)64 * NF_ * 4);       // 67.2 MB
  double* Sy1     = (double*)take(64 * 8);
  double* var1r   = (double*)take(64 * 8);
  float*  A1      = (float*)take(64 * 4);
  float*  Bc1     = (float*)take(64 * 4);
  double* S1      = (double*)take(64 * 8);
  double* mu2p    = (double*)take(128 * 8);
  float*  var2p   = (float*)take((size_t)512 * 128 * 4);
  double* var2r   = (double*)take(128 * 8);
  float*  A2      = (float*)take(128 * 4);
  float*  D2      = (float*)take(128 * 4);
  float*  s2p     = (float*)take((size_t)512 * 128 * 4);
  double* S2      = (double*)take(128 * 8);
  double* mu3p    = (double*)take(256 * 8);
  float*  var3p   = (float*)take((size_t)256 * 256 * 4);
  double* var3r   = (double*)take(256 * 8);
  float*  A3      = (float*)take(256 * 4);
  float*  D3      = (float*)take(256 * 4);

  if (off > ws_size) {
    diag_kernel<<<1, 64, 0, stream>>>(out, (float)(ws_size >> 20));
    return;
  }

  fps_kernel<<<B_, 64, 0, stream>>>(xy, fps_idx, new_xyz, out);
  knn_kernel<<<dim3((S_ + 31) / 32, B_), 256, 0, stream>>>(xy, fps_idx, knn_sel);
  pk_kernel<<<B_ * 32, 256, 0, stream>>>(fea, W1, P);
  yk1_kernel<<<NF_ / 256, 256, 0, stream>>>(xy, knn_sel, new_xyz, P, W1, b1, Y1);

  rowsum_kernel<false><<<64, 1024, 0, stream>>>(Y1, nullptr, nullptr, Sy1);
  rowvar_kernel<<<64, 1024, 0, stream>>>(Y1, Sy1, var1r);
  absch_kernel<<<1, 64, 0, stream>>>(Sy1, var1r, g1, be1, A1, Bc1, 64, 1);
  rowsum_kernel<true><<<64, 1024, 0, stream>>>(Y1, A1, Bc1, S1);

  meanlin_kernel<<<1, 128, 0, stream>>>(W2, S1, mu2p, 128, 64);
  pass2_kernel<0><<<512, 256, 0, stream>>>(Y1, W2, A1, Bc1, mu2p, nullptr, nullptr, var2p);
  red_kernel<<<1, 128, 0, stream>>>(var2p, var2r, 512, 128);
  absch_kernel<<<1, 128, 0, stream>>>(mu2p, var2r, g2, be2, A2, D2, 128, 0);

  pass2_kernel<1><<<512, 256, 0, stream>>>(Y1, W2, A1, Bc1, nullptr, A2, D2, s2p);
  red_kernel<<<1, 128, 0, stream>>>(s2p, S2, 512, 128);
  meanlin_kernel<<<1, 256, 0, stream>>>(W3, S2, mu3p, 256, 128);

  var3_kernel<<<256, 256, 0, stream>>>(Y1, W2, W3, A1, Bc1, A2, D2, mu3p, var3p);
  red_kernel<<<1, 256, 0, stream>>>(var3p, var3r, 256, 256);
  absch_kernel<<<1, 256, 0, stream>>>(mu3p, var3r, g3, be3, A3, D3, 256, 0);

  final_kernel<<<NCH_, 256, 0, stream>>>(Y1, W2, W3, A1, Bc1, A2, D2, A3, D3, out1);
}

// Round 6
// 3003.866 us; speedup vs baseline: 1.5358x; 1.0604x over previous
//
#include <hip/hip_runtime.h>
#include <math.h>

#define B_   16
#define N_   2048
#define S_   1025
#define K_   16
#define EMB_ 64
#define NF_  (B_ * S_ * K_)   // 262400
#define NCH_ (NF_ / 64)       // 4100 column-chunks of 64

typedef float v2f __attribute__((ext_vector_type(2)));

// ---------------- FPS: ONE WAVE per batch, fp32 bit-exact, pk-math + DPP reduce ----------
// d = rn(rn(dx*dx) + rn(dy*dy)), dx = rn(px + (-cx)) == rn(px - cx). No fma contraction
// (v_pk_mul + v_pk_add only). Running fminf == jnp.minimum; argmax lowest-index tie-break.
// Lane l owns contiguous points [l*32, l*32+32) -> (first lane, first local j) == np.argmax.
__global__ __launch_bounds__(64, 1) void fps_kernel(const float* __restrict__ xy,
                                                    int* __restrict__ fps_idx,
                                                    float* __restrict__ new_xyz,
                                                    float* __restrict__ out0) {
  const int b = blockIdx.x;
  const int lane = threadIdx.x;   // 0..63
  __shared__ float2 lxy[N_];      // 16 KB (centroid lookup only)
  const float* xb = xy + (size_t)b * 2 * N_;
  const float2* xb2 = (const float2*)xb;
  const float2* yb2 = (const float2*)(xb + N_);
  v2f pxp[16], pyp[16];           // pairs (pt 2q, pt 2q+1) -- forced to VGPR by asm operands
  float dist[32];
#pragma unroll
  for (int q = 0; q < 16; ++q) {
    float2 x01 = xb2[lane * 16 + q];
    float2 y01 = yb2[lane * 16 + q];
    int p = lane * 32 + 2 * q;
    lxy[p] = make_float2(x01.x, y01.x);
    lxy[p + 1] = make_float2(x01.y, y01.y);
    pxp[q].x = x01.x; pxp[q].y = x01.y;
    pyp[q].x = y01.x; pyp[q].y = y01.y;
    dist[2 * q] = __builtin_inff();
    dist[2 * q + 1] = __builtin_inff();
  }
  __syncthreads();   // single wave; orders LDS init vs reads
  int cur = 0;
  for (int t = 0; t < S_; ++t) {
    float2 c = lxy[cur];          // uniform-address broadcast read
    if (lane == 0) {
      fps_idx[b * S_ + t] = cur;
      new_xyz[(b * S_ + t) * 2 + 0] = c.x;
      new_xyz[(b * S_ + t) * 2 + 1] = c.y;
      out0[b * 2 * S_ + t] = c.x;
      out0[b * 2 * S_ + S_ + t] = c.y;
    }
    const float ncx = -c.x, ncy = -c.y;   // negation exact; pk_add(px,-cx) == rn(px-cx)
    v2f ncx2; ncx2.x = ncx; ncx2.y = ncx;
    v2f ncy2; ncy2.x = ncy; ncy2.y = ncy;
    float lmax0 = -__builtin_inff(), lmax1 = -__builtin_inff();
#pragma unroll
    for (int q = 0; q < 16; ++q) {
      v2f dx, dy, sx, sy, dd;
      asm("v_pk_add_f32 %0, %1, %2" : "=v"(dx) : "v"(pxp[q]), "v"(ncx2));
      asm("v_pk_add_f32 %0, %1, %2" : "=v"(dy) : "v"(pyp[q]), "v"(ncy2));
      asm("v_pk_mul_f32 %0, %1, %1" : "=v"(sx) : "v"(dx));
      asm("v_pk_mul_f32 %0, %1, %1" : "=v"(sy) : "v"(dy));
      asm("v_pk_add_f32 %0, %1, %2" : "=v"(dd) : "v"(sx), "v"(sy));
      float nd0 = fminf(dist[2 * q], dd.x);
      float nd1 = fminf(dist[2 * q + 1], dd.y);
      dist[2 * q] = nd0;
      dist[2 * q + 1] = nd1;
      lmax0 = fmaxf(lmax0, nd0);
      lmax1 = fmaxf(lmax1, nd1);
    }
    const float lmax = fmaxf(lmax0, lmax1);
    // DPP max all-reduce to lane 63 (pure VALU; invalid lanes keep old -> harmless for max)
    int xr = __float_as_int(lmax);
#define DPP_MAX_STEP(CTRL)                                                        \
    {                                                                             \
      int tmp_ = __builtin_amdgcn_update_dpp(xr, xr, (CTRL), 0xF, 0xF, false);    \
      xr = __float_as_int(fmaxf(__int_as_float(xr), __int_as_float(tmp_)));       \
    }
    DPP_MAX_STEP(0x111)  // row_shr:1
    DPP_MAX_STEP(0x112)  // row_shr:2
    DPP_MAX_STEP(0x114)  // row_shr:4
    DPP_MAX_STEP(0x118)  // row_shr:8   -> lane15 of each row = row max
    DPP_MAX_STEP(0x142)  // row_bcast:15 -> lane31 = max(0..31), lane63 = max(32..63)
    DPP_MAX_STEP(0x143)  // row_bcast:31 -> lane63 = global max
#undef DPP_MAX_STEP
    const float g = __int_as_float(__builtin_amdgcn_readlane(xr, 63));  // SGPR broadcast
    // first local index equal to g (descending scan keeps lowest j); bitwise == is exact
    int lf = 0;
#pragma unroll
    for (int j = 31; j >= 0; --j)
      if (dist[j] == g) lf = j;
    unsigned long long mask = __ballot(lmax == g);   // non-empty by construction
    int first = __ffsll(mask) - 1;                   // lowest lane with the max
    cur = __builtin_amdgcn_readlane(lane * 32 + lf, first);
  }
}

// ---------------- KNN fp64-exact, 16 lanes per query point, register bitonic merges ----------
// Lex order (d, idx) == stable top_k tie semantics. Downstream is k-max-pool -> only the SET matters.
__global__ __launch_bounds__(256) void knn_kernel(const float* __restrict__ xy,
                                                  const int* __restrict__ fps_idx,
                                                  int* __restrict__ knn_sel) {
  const int b = blockIdx.y;
  __shared__ float2 lxy[N_];    // 16 KB
  __shared__ double lsq[N_];    // 16 KB
  const float* xb = xy + (size_t)b * 2 * N_;
  for (int p = threadIdx.x; p < N_; p += 256) {
    float x = xb[p], y = xb[N_ + p];
    lxy[p] = make_float2(x, y);
    lsq[p] = (double)x * (double)x + (double)y * (double)y;  // exact
  }
  __syncthreads();
  const int t = threadIdx.x;
  const int s = blockIdx.x * 16 + (t >> 4);
  if (s >= S_) return;          // whole 16-lane group shares s -> uniform exit; shfl stays in-group
  const int oct = t & 15;
  const int p0 = fps_idx[b * S_ + s];
  float2 q = lxy[p0];
  const double xn = (double)q.x, yn = (double)q.y;
  const double sqn = lsq[p0];
  double d16[16];
  int i16[16];
#pragma unroll
  for (int j = 0; j < 16; ++j) { d16[j] = __builtin_inf(); i16[j] = 0x7fffffff; }
  const int mlo = oct * 128;
  for (int m0 = mlo; m0 < mlo + 128; m0 += 4) {
    double dd[4];
#pragma unroll
    for (int u = 0; u < 4; ++u) {
      float2 p = lxy[m0 + u];
      double dot = (double)p.x * xn + (double)p.y * yn;   // exact products -> fma == mul,mul,add
      dd[u] = (sqn - 2.0 * dot) + lsq[m0 + u];            // reference rounding order
    }
#pragma unroll
    for (int u = 0; u < 4; ++u) {
      if (dd[u] < d16[15]) {   // strict <: within ascending scan this is lex-correct
        double d = dd[u];
        int mi = m0 + u;
#pragma unroll
        for (int j = 15; j >= 1; --j) {
          bool shift = d < d16[j - 1];
          bool ins = d < d16[j];
          d16[j] = shift ? d16[j - 1] : (ins ? d : d16[j]);
          i16[j] = shift ? i16[j - 1] : (ins ? mi : i16[j]);
        }
        if (d < d16[0]) { d16[0] = d; i16[0] = mi; }
      }
    }
  }
  // 4 merge rounds across the 16-lane group (xor 1,2,4,8).
  // Half-cleaner: nd[i] = lexmin(a[i], rev_b[i]); rounds 1..3 re-sort (bitonic), last is set-only.
#pragma unroll
  for (int w = 1; w <= 8; w <<= 1) {
    double nd[16]; int ni[16];
#pragma unroll
    for (int i = 0; i < 16; ++i) {
      double rd = __shfl_xor(d16[15 - i], w, 64);
      int ri = __shfl_xor(i16[15 - i], w, 64);
      bool takeR = (rd < d16[i]) || (rd == d16[i] && ri < i16[i]);
      nd[i] = takeR ? rd : d16[i];
      ni[i] = takeR ? ri : i16[i];
    }
#pragma unroll
    for (int i = 0; i < 16; ++i) { d16[i] = nd[i]; i16[i] = ni[i]; }
    if (w < 8) {
#pragma unroll
      for (int dstg = 8; dstg >= 1; dstg >>= 1) {
#pragma unroll
        for (int i = 0; i < 16; ++i) {
          if ((i & dstg) == 0) {
            int a = i, c = i + dstg;
            bool sw = (d16[a] > d16[c]) || (d16[a] == d16[c] && i16[a] > i16[c]);
            double tlo = sw ? d16[c] : d16[a];
            double thi = sw ? d16[a] : d16[c];
            int ulo = sw ? i16[c] : i16[a];
            int uhi = sw ? i16[a] : i16[c];
            d16[a] = tlo; d16[c] = thi; i16[a] = ulo; i16[c] = uhi;
          }
        }
      }
    }
  }
  if (oct == 0) {
    int* dst = knn_sel + ((size_t)b * S_ + s) * K_;
#pragma unroll
    for (int j = 0; j < 16; ++j) dst[j] = i16[j];
  }
}

// ---------------- P[b][pt][c] = sum_e W1[c][2+e] * fea[b][e][pt] ----------------
__global__ __launch_bounds__(256) void pk_kernel(const float* __restrict__ fea,
                                                 const float* __restrict__ W1,
                                                 float* __restrict__ P) {
  const int t = threadIdx.x;
  const int b = blockIdx.x >> 5;
  const int pt0 = (blockIdx.x & 31) << 6;
  __shared__ float W1L[64 * 64];   // [e][c]
  __shared__ float feaL[64 * 64];  // [e][pt]
#pragma unroll
  for (int p = 0; p < 16; ++p) {
    int idx = t + 256 * p;
    int c = idx >> 6, e = idx & 63;
    W1L[e * 64 + c] = W1[c * 66 + 2 + e];
    int r = (t >> 6) + 4 * p, cc = t & 63;
    feaL[r * 64 + cc] = fea[((size_t)b * 64 + r) * N_ + pt0 + cc];
  }
  __syncthreads();
  const int tpt = t & 15, tcq = t >> 4;
  float acc[4][4];
#pragma unroll
  for (int i = 0; i < 4; ++i)
#pragma unroll
    for (int j = 0; j < 4; ++j) acc[i][j] = 0.f;
  for (int e = 0; e < 64; ++e) {
    float4 a4 = *reinterpret_cast<const float4*>(&W1L[e * 64 + tcq * 4]);
    float4 b4 = *reinterpret_cast<const float4*>(&feaL[e * 64 + tpt * 4]);
    const float av[4] = {a4.x, a4.y, a4.z, a4.w};
    const float bvv[4] = {b4.x, b4.y, b4.z, b4.w};
#pragma unroll
    for (int i = 0; i < 4; ++i)
#pragma unroll
      for (int j = 0; j < 4; ++j) acc[i][j] = fmaf(av[i], bvv[j], acc[i][j]);
  }
#pragma unroll
  for (int j = 0; j < 4; ++j) {
    int pt = tpt * 4 + j;
    float4 v = {acc[0][j], acc[1][j], acc[2][j], acc[3][j]};
    *reinterpret_cast<float4*>(&P[((size_t)(b * N_ + pt0 + pt)) * 64 + tcq * 4]) = v;
  }
}

// ---------------- Y1[64][NF]: gather P + W1a*dxy + b1 ----------------
__global__ __launch_bounds__(256) void yk1_kernel(const float* __restrict__ xy,
                                                  const int* __restrict__ knn_sel,
                                                  const float* __restrict__ new_xyz,
                                                  const float* __restrict__ P,
                                                  const float* __restrict__ W1,
                                                  const float* __restrict__ b1,
                                                  float* __restrict__ Y1) {
  __shared__ float w0s[64], w1s[64], bbs[64];
  const int t = threadIdx.x;
  if (t < 64) { w0s[t] = W1[t * 66 + 0]; w1s[t] = W1[t * 66 + 1]; bbs[t] = b1[t]; }
  __syncthreads();
  const int n = blockIdx.x * 256 + t;
  const int bs = n >> 4;
  const int b = bs / S_;
  const int nbr = knn_sel[n];
  const float dx = xy[(size_t)b * 2 * N_ + nbr] - new_xyz[bs * 2 + 0];
  const float dy = xy[(size_t)b * 2 * N_ + N_ + nbr] - new_xyz[bs * 2 + 1];
  const float* prow = &P[((size_t)(b * N_ + nbr)) * 64];
  for (int c4 = 0; c4 < 64; c4 += 4) {
    float4 p4 = *reinterpret_cast<const float4*>(&prow[c4]);
    float v0 = p4.x + w0s[c4 + 0] * dx + w1s[c4 + 0] * dy + bbs[c4 + 0];
    float v1 = p4.y + w0s[c4 + 1] * dx + w1s[c4 + 1] * dy + bbs[c4 + 1];
    float v2 = p4.z + w0s[c4 + 2] * dx + w1s[c4 + 2] * dy + bbs[c4 + 2];
    float v3 = p4.w + w0s[c4 + 3] * dx + w1s[c4 + 3] * dy + bbs[c4 + 3];
    Y1[(size_t)(c4 + 0) * NF_ + n] = v0;
    Y1[(size_t)(c4 + 1) * NF_ + n] = v1;
    Y1[(size_t)(c4 + 2) * NF_ + n] = v2;
    Y1[(size_t)(c4 + 3) * NF_ + n] = v3;
  }
}

// ---------------- per-row sum (optionally affine+relu), double accumulators ----------------
template <bool AFF>
__global__ __launch_bounds__(1024) void rowsum_kernel(const float* __restrict__ Y,
                                                      const float* __restrict__ A,
                                                      const float* __restrict__ Bc,
                                                      double* __restrict__ out) {
  const int r = blockIdx.x;
  const float a = AFF ? A[r] : 0.f, c = AFF ? Bc[r] : 0.f;
  double s = 0.0;
  for (int i = threadIdx.x; i < NF_; i += 1024) {
    float v = Y[(size_t)r * NF_ + i];
    if (AFF) v = fmaxf(fmaf(v, a, c), 0.f);
    s += (double)v;
  }
  __shared__ double sh[1024];
  sh[threadIdx.x] = s;
  __syncthreads();
  for (int o = 512; o > 0; o >>= 1) {
    if (threadIdx.x < o) sh[threadIdx.x] += sh[threadIdx.x + o];
    __syncthreads();
  }
  if (threadIdx.x == 0) out[r] = sh[0];
}

// ---------------- per-row centered sumsq ----------------
__global__ __launch_bounds__(1024) void rowvar_kernel(const float* __restrict__ Y,
                                                      const double* __restrict__ sums,
                                                      double* __restrict__ out) {
  const int r = blockIdx.x;
  const double mu = sums[r] * (1.0 / NF_);
  double s = 0.0;
  for (int i = threadIdx.x; i < NF_; i += 1024) {
    double d = (double)Y[(size_t)r * NF_ + i] - mu;
    s += d * d;
  }
  __shared__ double sh[1024];
  sh[threadIdx.x] = s;
  __syncthreads();
  for (int o = 512; o > 0; o >>= 1) {
    if (threadIdx.x < o) sh[threadIdx.x] += sh[threadIdx.x + o];
    __syncthreads();
  }
  if (threadIdx.x == 0) out[r] = sh[0];
}

// ---------------- A = g*rsqrt(var+eps); D = be - A*mu ----------------
__global__ void absch_kernel(const double* __restrict__ muv, const double* __restrict__ varraw,
                             const float* __restrict__ g, const float* __restrict__ be,
                             float* __restrict__ A, float* __restrict__ D, int M, int mu_is_sum) {
  int m = threadIdx.x;
  if (m >= M) return;
  double mu = mu_is_sum ? muv[m] * (1.0 / NF_) : muv[m];
  double var = varraw[m] * (1.0 / NF_);
  double a = (double)g[m] / sqrt(var + 1e-5);
  A[m] = (float)a;
  D[m] = (float)((double)be[m] - a * mu);
}

// ---------------- mu[m] = dot(W[m,:K], S)/NF ----------------
__global__ void meanlin_kernel(const float* __restrict__ W, const double* __restrict__ S,
                               double* __restrict__ mu, int M, int K) {
  int m = threadIdx.x;
  if (m >= M) return;
  double acc = 0.0;
  for (int k = 0; k < K; ++k) acc += (double)W[m * K + k] * S[k];
  mu[m] = acc * (1.0 / NF_);
}

// ---------------- reduce partials [P][M] -> double[M] ----------------
__global__ void red_kernel(const float* __restrict__ parts, double* __restrict__ out, int P, int M) {
  int m = threadIdx.x;
  if (m >= M) return;
  double a = 0.0;
  for (int p = 0; p < P; ++p) a += (double)parts[(size_t)p * M + m];
  out[m] = a;
}

// ============ GEMM2 pass kernels: y2[128][64cols] per chunk, x1 from Y1 on the fly ============
template <int MODE>  // 0: accumulate (y2-mu2')^2 ; 1: accumulate relu(A2*y2+D2)
__global__ __launch_bounds__(256) void pass2_kernel(const float* __restrict__ Y1,
                                                    const float* __restrict__ W2,
                                                    const float* __restrict__ A1v,
                                                    const float* __restrict__ Bc1v,
                                                    const double* __restrict__ mu2p,
                                                    const float* __restrict__ A2v,
                                                    const float* __restrict__ D2v,
                                                    float* __restrict__ parts) {
  __shared__ float W2L[64 * 128];
  __shared__ float ab[128];
  __shared__ float vpart[16][128];
  const int t = threadIdx.x;
#pragma unroll
  for (int p = 0; p < 32; ++p) {
    int idx = t + 256 * p;
    int m = idx >> 6, k = idx & 63;
    W2L[k * 128 + m] = W2[m * 64 + k];
  }
  if (t < 64) { ab[t] = A1v[t]; ab[64 + t] = Bc1v[t]; }
  const int tmA = t >> 4, tcA = t & 15;
  float par0[8], par1[8], vacc[8];
#pragma unroll
  for (int i = 0; i < 8; ++i) {
    int m = tmA * 8 + i;
    if (MODE == 0) { par0[i] = (float)mu2p[m]; par1[i] = 0.f; }
    else { par0[i] = A2v[m]; par1[i] = D2v[m]; }
    vacc[i] = 0.f;
  }
  __syncthreads();
  for (int ch = blockIdx.x; ch < NCH_; ch += 512) {
    const size_t n0 = (size_t)ch * 64;
    float acc[8][4];
#pragma unroll
    for (int i = 0; i < 8; ++i)
#pragma unroll
      for (int j = 0; j < 4; ++j) acc[i][j] = 0.f;
#pragma unroll 2
    for (int k = 0; k < 64; ++k) {
      float4 y4 = *reinterpret_cast<const float4*>(&Y1[(size_t)k * NF_ + n0 + tcA * 4]);
      float a1 = ab[k], c1 = ab[64 + k];
      float bx[4];
      bx[0] = fmaxf(fmaf(y4.x, a1, c1), 0.f);
      bx[1] = fmaxf(fmaf(y4.y, a1, c1), 0.f);
      bx[2] = fmaxf(fmaf(y4.z, a1, c1), 0.f);
      bx[3] = fmaxf(fmaf(y4.w, a1, c1), 0.f);
      const float4* ap = reinterpret_cast<const float4*>(&W2L[k * 128 + tmA * 8]);
      float4 a0 = ap[0], a4 = ap[1];
      const float av[8] = {a0.x, a0.y, a0.z, a0.w, a4.x, a4.y, a4.z, a4.w};
#pragma unroll
      for (int i = 0; i < 8; ++i)
#pragma unroll
        for (int j = 0; j < 4; ++j) acc[i][j] = fmaf(av[i], bx[j], acc[i][j]);
    }
#pragma unroll
    for (int i = 0; i < 8; ++i)
#pragma unroll
      for (int j = 0; j < 4; ++j) {
        if (MODE == 0) {
          float d = acc[i][j] - par0[i];
          vacc[i] = fmaf(d, d, vacc[i]);
        } else {
          vacc[i] += fmaxf(fmaf(acc[i][j], par0[i], par1[i]), 0.f);
        }
      }
  }
#pragma unroll
  for (int i = 0; i < 8; ++i) vpart[tcA][tmA * 8 + i] = vacc[i];
  __syncthreads();
  if (t < 128) {
    float s = 0.f;
    for (int q = 0; q < 16; ++q) s += vpart[q][t];
    parts[(size_t)blockIdx.x * 128 + t] = s;
  }
}

// ============ var3 pass: y3 = W3 * relu(A2*(W2*x1)+D2), accumulate (y3-mu3')^2 ============
__global__ __launch_bounds__(256) void var3_kernel(const float* __restrict__ Y1,
                                                   const float* __restrict__ W2,
                                                   const float* __restrict__ W3,
                                                   const float* __restrict__ A1v,
                                                   const float* __restrict__ Bc1v,
                                                   const float* __restrict__ A2v,
                                                   const float* __restrict__ D2v,
                                                   const double* __restrict__ mu3p,
                                                   float* __restrict__ parts) {
  __shared__ float W2L[64 * 128];     // persistent
  __shared__ float ab[128];
  __shared__ float X2s[128 * 68];
  __shared__ float W3c[16 * 256];
  __shared__ float vpart3[8][256];
  const int t = threadIdx.x;
#pragma unroll
  for (int p = 0; p < 32; ++p) {
    int idx = t + 256 * p;
    int m = idx >> 6, k = idx & 63;
    W2L[k * 128 + m] = W2[m * 64 + k];
  }
  if (t < 64) { ab[t] = A1v[t]; ab[64 + t] = Bc1v[t]; }
  const int tmA = t >> 4, tcA = t & 15;
  const int tm3 = t & 31, tcol = t >> 5;
  float a2r[8], d2r[8], mu3[8], vacc[8];
#pragma unroll
  for (int i = 0; i < 8; ++i) {
    a2r[i] = A2v[tmA * 8 + i];
    d2r[i] = D2v[tmA * 8 + i];
    mu3[i] = (float)mu3p[tm3 * 8 + i];
    vacc[i] = 0.f;
  }
  __syncthreads();
  for (int ch = blockIdx.x; ch < NCH_; ch += 256) {
    const size_t n0 = (size_t)ch * 64;
    {
      float acc[8][4];
#pragma unroll
      for (int i = 0; i < 8; ++i)
#pragma unroll
        for (int j = 0; j < 4; ++j) acc[i][j] = 0.f;
#pragma unroll 2
      for (int k = 0; k < 64; ++k) {
        float4 y4 = *reinterpret_cast<const float4*>(&Y1[(size_t)k * NF_ + n0 + tcA * 4]);
        float a1 = ab[k], c1 = ab[64 + k];
        float bx[4];
        bx[0] = fmaxf(fmaf(y4.x, a1, c1), 0.f);
        bx[1] = fmaxf(fmaf(y4.y, a1, c1), 0.f);
        bx[2] = fmaxf(fmaf(y4.z, a1, c1), 0.f);
        bx[3] = fmaxf(fmaf(y4.w, a1, c1), 0.f);
        const float4* ap = reinterpret_cast<const float4*>(&W2L[k * 128 + tmA * 8]);
        float4 a0 = ap[0], a4 = ap[1];
        const float av[8] = {a0.x, a0.y, a0.z, a0.w, a4.x, a4.y, a4.z, a4.w};
#pragma unroll
        for (int i = 0; i < 8; ++i)
#pragma unroll
          for (int j = 0; j < 4; ++j) acc[i][j] = fmaf(av[i], bx[j], acc[i][j]);
      }
#pragma unroll
      for (int i = 0; i < 8; ++i) {
        float4 v;
        v.x = fmaxf(fmaf(acc[i][0], a2r[i], d2r[i]), 0.f);
        v.y = fmaxf(fmaf(acc[i][1], a2r[i], d2r[i]), 0.f);
        v.z = fmaxf(fmaf(acc[i][2], a2r[i], d2r[i]), 0.f);
        v.w = fmaxf(fmaf(acc[i][3], a2r[i], d2r[i]), 0.f);
        *reinterpret_cast<float4*>(&X2s[(tmA * 8 + i) * 68 + tcA * 4]) = v;
      }
    }
    __syncthreads();
    float acc3[8][8];
#pragma unroll
    for (int i = 0; i < 8; ++i)
#pragma unroll
      for (int j = 0; j < 8; ++j) acc3[i][j] = 0.f;
    for (int kc = 0; kc < 8; ++kc) {
#pragma unroll
      for (int q = 0; q < 4; ++q) {
        float4 w = *reinterpret_cast<const float4*>(&W3[(size_t)t * 128 + kc * 16 + q * 4]);
        W3c[(q * 4 + 0) * 256 + t] = w.x;
        W3c[(q * 4 + 1) * 256 + t] = w.y;
        W3c[(q * 4 + 2) * 256 + t] = w.z;
        W3c[(q * 4 + 3) * 256 + t] = w.w;
      }
      __syncthreads();
#pragma unroll
      for (int kk = 0; kk < 16; ++kk) {
        const float4* ap = reinterpret_cast<const float4*>(&W3c[kk * 256 + tm3 * 8]);
        float4 a0 = ap[0], a4 = ap[1];
        const float4* bp = reinterpret_cast<const float4*>(&X2s[(kc * 16 + kk) * 68 + tcol * 8]);
        float4 b0 = bp[0], b4 = bp[1];
        const float av[8] = {a0.x, a0.y, a0.z, a0.w, a4.x, a4.y, a4.z, a4.w};
        const float bw[8] = {b0.x, b0.y, b0.z, b0.w, b4.x, b4.y, b4.z, b4.w};
#pragma unroll
        for (int i = 0; i < 8; ++i)
#pragma unroll
          for (int j = 0; j < 8; ++j) acc3[i][j] = fmaf(av[i], bw[j], acc3[i][j]);
      }
      __syncthreads();
    }
#pragma unroll
    for (int i = 0; i < 8; ++i)
#pragma unroll
      for (int j = 0; j < 8; ++j) {
        float d = acc3[i][j] - mu3[i];
        vacc[i] = fmaf(d, d, vacc[i]);
      }
    __syncthreads();
  }
#pragma unroll
  for (int i = 0; i < 8; ++i) vpart3[tcol][tm3 * 8 + i] = vacc[i];
  __syncthreads();
  {
    float s = 0.f;
    for (int q = 0; q < 8; ++q) s += vpart3[q][t];
    parts[(size_t)blockIdx.x * 256 + t] = s;
  }
}

// ============ final pass: GEMM2 -> BN -> relu -> GEMM3 -> BN -> max over k -> relu -> out1 ============
__global__ __launch_bounds__(256) void final_kernel(const float* __restrict__ Y1,
                                                    const float* __restrict__ W2,
                                                    const float* __restrict__ W3,
                                                    const float* __restrict__ A1v,
                                                    const float* __restrict__ Bc1v,
                                                    const float* __restrict__ A2v,
                                                    const float* __restrict__ D2v,
                                                    const float* __restrict__ A3v,
                                                    const float* __restrict__ D3v,
                                                    float* __restrict__ out1) {
  __shared__ float W2L[64 * 128];   // aliased as W3c in phase B
  __shared__ float ab[128];
  __shared__ float X2s[128 * 68];
  float* W3c = W2L;
  const int t = threadIdx.x;
#pragma unroll
  for (int p = 0; p < 32; ++p) {
    int idx = t + 256 * p;
    int m = idx >> 6, k = idx & 63;
    W2L[k * 128 + m] = W2[m * 64 + k];
  }
  if (t < 64) { ab[t] = A1v[t]; ab[64 + t] = Bc1v[t]; }
  const int tmA = t >> 4, tcA = t & 15;
  const int tm3 = t & 31, tcol = t >> 5;
  float a2r[8], d2r[8], a3r[8], d3r[8];
#pragma unroll
  for (int i = 0; i < 8; ++i) {
    a2r[i] = A2v[tmA * 8 + i];
    d2r[i] = D2v[tmA * 8 + i];
    a3r[i] = A3v[tm3 * 8 + i];
    d3r[i] = D3v[tm3 * 8 + i];
  }
  __syncthreads();
  const int ch = blockIdx.x;
  const size_t n0 = (size_t)ch * 64;
  {
    float acc[8][4];
#pragma unroll
    for (int i = 0; i < 8; ++i)
#pragma unroll
      for (int j = 0; j < 4; ++j) acc[i][j] = 0.f;
#pragma unroll 2
    for (int k = 0; k < 64; ++k) {
      float4 y4 = *reinterpret_cast<const float4*>(&Y1[(size_t)k * NF_ + n0 + tcA * 4]);
      float a1 = ab[k], c1 = ab[64 + k];
      float bx[4];
      bx[0] = fmaxf(fmaf(y4.x, a1, c1), 0.f);
      bx[1] = fmaxf(fmaf(y4.y, a1, c1), 0.f);
      bx[2] = fmaxf(fmaf(y4.z, a1, c1), 0.f);
      bx[3] = fmaxf(fmaf(y4.w, a1, c1), 0.f);
      const float4* ap = reinterpret_cast<const float4*>(&W2L[k * 128 + tmA * 8]);
      float4 a0 = ap[0], a4 = ap[1];
      const float av[8] = {a0.x, a0.y, a0.z, a0.w, a4.x, a4.y, a4.z, a4.w};
#pragma unroll
      for (int i = 0; i < 8; ++i)
#pragma unroll
        for (int j = 0; j < 4; ++j) acc[i][j] = fmaf(av[i], bx[j], acc[i][j]);
    }
#pragma unroll
    for (int i = 0; i < 8; ++i) {
      float4 v;
      v.x = fmaxf(fmaf(acc[i][0], a2r[i], d2r[i]), 0.f);
      v.y = fmaxf(fmaf(acc[i][1], a2r[i], d2r[i]), 0.f);
      v.z = fmaxf(fmaf(acc[i][2], a2r[i], d2r[i]), 0.f);
      v.w = fmaxf(fmaf(acc[i][3], a2r[i], d2r[i]), 0.f);
      *reinterpret_cast<float4*>(&X2s[(tmA * 8 + i) * 68 + tcA * 4]) = v;
    }
  }
  __syncthreads();
  float acc3[8][8];
#pragma unroll
  for (int i = 0; i < 8; ++i)
#pragma unroll
    for (int j = 0; j < 8; ++j) acc3[i][j] = 0.f;
  for (int kc = 0; kc < 8; ++kc) {
#pragma unroll
    for (int q = 0; q < 4; ++q) {
      float4 w = *reinterpret_cast<const float4*>(&W3[(size_t)t * 128 + kc * 16 + q * 4]);
      W3c[(q * 4 + 0) * 256 + t] = w.x;
      W3c[(q * 4 + 1) * 256 + t] = w.y;
      W3c[(q * 4 + 2) * 256 + t] = w.z;
      W3c[(q * 4 + 3) * 256 + t] = w.w;
    }
    __syncthreads();
#pragma unroll
    for (int kk = 0; kk < 16; ++kk) {
      const float4* ap = reinterpret_cast<const float4*>(&W3c[kk * 256 + tm3 * 8]);
      float4 a0 = ap[0], a4 = ap[1];
      const float4* bp = reinterpret_cast<const float4*>(&X2s[(kc * 16 + kk) * 68 + tcol * 8]);
      float4 b0 = bp[0], b4 = bp[1];
      const float av[8] = {a0.x, a0.y, a0.z, a0.w, a4.x, a4.y, a4.z, a4.w};
      const float bw[8] = {b0.x, b0.y, b0.z, b0.w, b4.x, b4.y, b4.z, b4.w};
#pragma unroll
      for (int i = 0; i < 8; ++i)
#pragma unroll
        for (int j = 0; j < 8; ++j) acc3[i][j] = fmaf(av[i], bw[j], acc3[i][j]);
    }
    __syncthreads();
  }
#pragma unroll
  for (int i = 0; i < 8; ++i) {
    float mx = -__builtin_inff();
#pragma unroll
    for (int j = 0; j < 8; ++j) {
      float v = fmaf(acc3[i][j], a3r[i], d3r[i]);
      mx = fmaxf(mx, v);
    }
    float o = __shfl_xor(mx, 32, 64);
    mx = fmaxf(mx, o);
    if ((tcol & 1) == 0) {
      int g = tcol >> 1;
      int bs = ch * 4 + g;
      int b = bs / S_;
      int s = bs - b * S_;
      out1[((size_t)(b * 256 + tm3 * 8 + i)) * S_ + s] = fmaxf(mx, 0.f);
    }
  }
}

__global__ void diag_kernel(float* out, float v) {
  if (threadIdx.x == 0 && blockIdx.x == 0) out[0] = v;
}

extern "C" void kernel_launch(void* const* d_in, const int* in_sizes, int n_in,
                              void* d_out, int out_size, void* d_ws, size_t ws_size,
                              hipStream_t stream) {
  const float* xy  = (const float*)d_in[0];
  const float* fea = (const float*)d_in[1];
  const float* W1  = (const float*)d_in[2];
  const float* b1  = (const float*)d_in[3];
  const float* g1  = (const float*)d_in[4];
  const float* be1 = (const float*)d_in[5];
  const float* W2  = (const float*)d_in[6];
  const float* b2  = (const float*)d_in[7];
  const float* g2  = (const float*)d_in[8];
  const float* be2 = (const float*)d_in[9];
  const float* W3  = (const float*)d_in[10];
  const float* b3  = (const float*)d_in[11];
  const float* g3  = (const float*)d_in[12];
  const float* be3 = (const float*)d_in[13];
  (void)b2; (void)b3;
  float* out = (float*)d_out;
  float* out1 = out + B_ * 2 * S_;

  char* w = (char*)d_ws;
  size_t off = 0;
  auto take = [&](size_t bytes) -> void* {
    void* p = w + off;
    off += (bytes + 255) & ~(size_t)255;
    return p;
  };
  int*    fps_idx = (int*)take((size_t)B_ * S_ * 4);
  float*  new_xyz = (float*)take((size_t)B_ * S_ * 2 * 4);
  int*    knn_sel = (int*)take((size_t)NF_ * 4);
  float*  P       = (float*)take((size_t)B_ * N_ * 64 * 4);   // 8.4 MB
  float*  Y1      = (float*)take((size_t)64 * NF_ * 4);       // 67.2 MB
  double* Sy1     = (double*)take(64 * 8);
  double* var1r   = (double*)take(64 * 8);
  float*  A1      = (float*)take(64 * 4);
  float*  Bc1     = (float*)take(64 * 4);
  double* S1      = (double*)take(64 * 8);
  double* mu2p    = (double*)take(128 * 8);
  float*  var2p   = (float*)take((size_t)512 * 128 * 4);
  double* var2r   = (double*)take(128 * 8);
  float*  A2      = (float*)take(128 * 4);
  float*  D2      = (float*)take(128 * 4);
  float*  s2p     = (float*)take((size_t)512 * 128 * 4);
  double* S2      = (double*)take(128 * 8);
  double* mu3p    = (double*)take(256 * 8);
  float*  var3p   = (float*)take((size_t)256 * 256 * 4);
  double* var3r   = (double*)take(256 * 8);
  float*  A3      = (float*)take(256 * 4);
  float*  D3      = (float*)take(256 * 4);

  if (off > ws_size) {
    diag_kernel<<<1, 64, 0, stream>>>(out, (float)(ws_size >> 20));
    return;
  }

  fps_kernel<<<B_, 64, 0, stream>>>(xy, fps_idx, new_xyz, out);
  knn_kernel<<<dim3((S_ + 15) / 16, B_), 256, 0, stream>>>(xy, fps_idx, knn_sel);
  pk_kernel<<<B_ * 32, 256, 0, stream>>>(fea, W1, P);
  yk1_kernel<<<NF_ / 256, 256, 0, stream>>>(xy, knn_sel, new_xyz, P, W1, b1, Y1);

  rowsum_kernel<false><<<64, 1024, 0, stream>>>(Y1, nullptr, nullptr, Sy1);
  rowvar_kernel<<<64, 1024, 0, stream>>>(Y1, Sy1, var1r);
  absch_kernel<<<1, 64, 0, stream>>>(Sy1, var1r, g1, be1, A1, Bc1, 64, 1);
  rowsum_kernel<true><<<64, 1024, 0, stream>>>(Y1, A1, Bc1, S1);

  meanlin_kernel<<<1, 128, 0, stream>>>(W2, S1, mu2p, 128, 64);
  pass2_kernel<0><<<512, 256, 0, stream>>>(Y1, W2, A1, Bc1, mu2p, nullptr, nullptr, var2p);
  red_kernel<<<1, 128, 0, stream>>>(var2p, var2r, 512, 128);
  absch_kernel<<<1, 128, 0, stream>>>(mu2p, var2r, g2, be2, A2, D2, 128, 0);

  pass2_kernel<1><<<512, 256, 0, stream>>>(Y1, W2, A1, Bc1, nullptr, A2, D2, s2p);
  red_kernel<<<1, 128, 0, stream>>>(s2p, S2, 512, 128);
  meanlin_kernel<<<1, 256, 0, stream>>>(W3, S2, mu3p, 256, 128);

  var3_kernel<<<256, 256, 0, stream>>>(Y1, W2, W3, A1, Bc1, A2, D2, mu3p, var3p);
  red_kernel<<<1, 256, 0, stream>>>(var3p, var3r, 256, 256);
  absch_kernel<<<1, 256, 0, stream>>>(mu3p, var3r, g3, be3, A3, D3, 256, 0);

  final_kernel<<<NCH_, 256, 0, stream>>>(Y1, W2, W3, A1, Bc1, A2, D2, A3, D3, out1);
}